// Round 5
// baseline (662.307 us; speedup 1.0000x reference)
//
#include <hip/hip_runtime.h>
#include <hip/hip_bf16.h>

#define NN 50000
#define NE 800000
#define H 128
#define DE 16
#define BN_EPS 1e-5f

typedef float v2f __attribute__((ext_vector_type(2)));
typedef float v4f __attribute__((ext_vector_type(4)));

__device__ __forceinline__ unsigned int packbf2(float a, float b) {
    __hip_bfloat162 h = __float22bfloat162_rn(make_float2(a, b));
    return *(unsigned int*)&h;
}
__device__ __forceinline__ v2f unpackbf2(unsigned int u) {
    v2f r;
    r.x = __uint_as_float(u << 16);
    r.y = __uint_as_float(u & 0xffff0000u);
    return r;
}

// ---------------- CSR build ----------------
__global__ void hist_k(const int* __restrict__ dst, int* __restrict__ counts) {
    int e = blockIdx.x * 256 + threadIdx.x;
    if (e < NE) atomicAdd(&counts[dst[e]], 1);
}

__global__ void dinv_k(const int* __restrict__ counts, float* __restrict__ dinv) {
    int i = blockIdx.x * 256 + threadIdx.x;
    if (i < NN) dinv[i] = rsqrtf((float)counts[i] + 1.0f);
}

__global__ __launch_bounds__(1024) void scan_k(const int* __restrict__ counts,
                                               int* __restrict__ offsets,
                                               int* __restrict__ cursor) {
    __shared__ int part[1024];
    int t = threadIdx.x;
    const int CH = (NN + 1023) / 1024;  // 49
    int lo = t * CH, hi = min(lo + CH, NN);
    int s = 0;
    for (int i = lo; i < hi; i++) s += counts[i];
    part[t] = s;
    __syncthreads();
    for (int off = 1; off < 1024; off <<= 1) {
        int v = 0;
        if (t >= off) v = part[t - off];
        __syncthreads();
        part[t] += v;
        __syncthreads();
    }
    int run = part[t] - s;  // exclusive prefix
    for (int i = lo; i < hi; i++) {
        offsets[i] = run;
        cursor[i]  = run;
        run += counts[i];
    }
}

// CSR payload: SoA (src id, original edge id); pads tail with zeros so
// grouped/pipelined reads past cnt are always safe.
__global__ void fill_k(const int* __restrict__ src, const int* __restrict__ dst,
                       int* __restrict__ cursor, int* __restrict__ srcs,
                       int* __restrict__ eids) {
    int e = blockIdx.x * 256 + threadIdx.x;
    if (e < NE) {
        int pos = atomicAdd(&cursor[dst[e]], 1);
        srcs[pos] = src[e];
        eids[pos] = e;
        if (e < 8) {            // zero padding beyond NE
            srcs[NE + e] = 0;
            eids[NE + e] = 0;
        }
    }
}

// ---------------- GEMM: C[M x 128] = A'[M x 128] @ B[128 x 128] ----------------
__global__ __launch_bounds__(256) void gemm128(const float* __restrict__ A,
                                               const float* __restrict__ B,
                                               float* __restrict__ C,
                                               unsigned int* __restrict__ Cb,
                                               const float* __restrict__ rowScale,
                                               const float* __restrict__ tA,
                                               const float* __restrict__ tC,
                                               int M) {
    __shared__ float As[64][36];    // [row][k] padded
    __shared__ float Bs[32][128];   // [k][col]
    int tid = threadIdx.x;
    int tx = tid & 31;
    int ty = tid >> 5;
    int cx = tx * 4;
    int rb = blockIdx.x * 64;

    v4f acc[8];
#pragma unroll
    for (int j = 0; j < 8; j++) acc[j] = (v4f)0.f;

    for (int kb = 0; kb < 128; kb += 32) {
        const float* Bsrc = B + kb * 128;
#pragma unroll
        for (int i = 0; i < 4; i++) {
            int l = 4 * (tid + 256 * i);
            *(float4*)&Bs[l >> 7][l & 127] = *(const float4*)&Bsrc[l];
        }
#pragma unroll
        for (int half = 0; half < 2; half++) {
            int ar = (tid >> 3) + half * 32;
            int ac = (tid & 7) * 4;
            int r = rb + ar;
            float4 av = make_float4(0.f, 0.f, 0.f, 0.f);
            if (r < M) av = *(const float4*)&A[(size_t)r * 128 + kb + ac];
            if (tA) {
                float4 a4 = *(const float4*)&tA[kb + ac];
                float4 c4 = *(const float4*)&tC[kb + ac];
                av.x = fmaxf(av.x * a4.x + c4.x, 0.f);
                av.y = fmaxf(av.y * a4.y + c4.y, 0.f);
                av.z = fmaxf(av.z * a4.z + c4.z, 0.f);
                av.w = fmaxf(av.w * a4.w + c4.w, 0.f);
            }
            *(float4*)&As[ar][ac] = av;
        }
        __syncthreads();
#pragma unroll
        for (int k = 0; k < 32; k += 4) {
            v4f b0 = *(v4f*)&Bs[k][cx];
            v4f b1 = *(v4f*)&Bs[k + 1][cx];
            v4f b2 = *(v4f*)&Bs[k + 2][cx];
            v4f b3 = *(v4f*)&Bs[k + 3][cx];
#pragma unroll
            for (int j = 0; j < 8; j++) {
                v4f a4 = *(v4f*)&As[ty * 8 + j][k];
                acc[j] += b0 * a4.x;
                acc[j] += b1 * a4.y;
                acc[j] += b2 * a4.z;
                acc[j] += b3 * a4.w;
            }
        }
        __syncthreads();
    }
#pragma unroll
    for (int j = 0; j < 8; j++) {
        int r = rb + ty * 8 + j;
        if (r < M) {
            float s = rowScale ? rowScale[r] : 1.f;
            v4f a = acc[j] * s;
            if (Cb) {
                uint2 pk;
                pk.x = packbf2(a.x, a.y);
                pk.y = packbf2(a.z, a.w);
                *(uint2*)&Cb[((size_t)r * 128 + cx) >> 1] = pk;
            } else {
                *(v4f*)&C[(size_t)r * 128 + cx] = a;
            }
        }
    }
}

// ---------------- aggregation: z[n] = dinv[n]*(sum_{e->n} hs[src] + hs[n]) + b ----------------
// 16-lane-per-row layout: slot g = lane>>4 (4 edge slots), fl = lane&15 (8 feats).
// One vmem instr gathers 4 rows (1 KB); unroll 2 groups -> 8 edges / 2 vmem instrs.
__global__ __launch_bounds__(256) void aggregate_k(const unsigned int* __restrict__ hsb,
                                                   const int* __restrict__ offsets,
                                                   const int* __restrict__ counts,
                                                   const int* __restrict__ srcs,
                                                   const float* __restrict__ dinv,
                                                   const float* __restrict__ bias,
                                                   float* __restrict__ zout) {
    int lane = threadIdx.x & 63;
    int n = __builtin_amdgcn_readfirstlane(blockIdx.x * 4 + (threadIdx.x >> 6));
    if (n >= NN) return;
    int beg = offsets[n];   // uniform
    int cnt = counts[n];    // uniform
    const int* ss = srcs + beg;
    int g = lane >> 4;
    int fl = lane & 15;

    v2f a0 = {0.f, 0.f}, a1 = {0.f, 0.f}, a2 = {0.f, 0.f}, a3 = {0.f, 0.f};
    v2f b0 = {0.f, 0.f}, b1 = {0.f, 0.f}, b2 = {0.f, 0.f}, b3 = {0.f, 0.f};

    int full = cnt & ~3;
    int t = 0;
    for (; t + 8 <= full; t += 8) {
        int s0 = ss[t],     s1 = ss[t + 1], s2 = ss[t + 2], s3 = ss[t + 3];
        int s4 = ss[t + 4], s5 = ss[t + 5], s6 = ss[t + 6], s7 = ss[t + 7];
        int sa = g < 2 ? (g == 0 ? s0 : s1) : (g == 2 ? s2 : s3);
        int sb = g < 2 ? (g == 0 ? s4 : s5) : (g == 2 ? s6 : s7);
        uint4 ua = *(const uint4*)&hsb[(size_t)sa * 64 + fl * 4];
        uint4 ub = *(const uint4*)&hsb[(size_t)sb * 64 + fl * 4];
        a0 += unpackbf2(ua.x); a1 += unpackbf2(ua.y);
        a2 += unpackbf2(ua.z); a3 += unpackbf2(ua.w);
        b0 += unpackbf2(ub.x); b1 += unpackbf2(ub.y);
        b2 += unpackbf2(ub.z); b3 += unpackbf2(ub.w);
    }
    if (t < full) {
        int s0 = ss[t], s1 = ss[t + 1], s2 = ss[t + 2], s3 = ss[t + 3];
        int sa = g < 2 ? (g == 0 ? s0 : s1) : (g == 2 ? s2 : s3);
        uint4 ua = *(const uint4*)&hsb[(size_t)sa * 64 + fl * 4];
        a0 += unpackbf2(ua.x); a1 += unpackbf2(ua.y);
        a2 += unpackbf2(ua.z); a3 += unpackbf2(ua.w);
        t += 4;
    }
    if (t < cnt) {  // masked tail group (reads past cnt are padded/valid, masked out)
        int s0 = ss[t], s1 = ss[t + 1], s2 = ss[t + 2], s3 = ss[t + 3];
        int sa = g < 2 ? (g == 0 ? s0 : s1) : (g == 2 ? s2 : s3);
        if (t + g < cnt) {
            uint4 ua = *(const uint4*)&hsb[(size_t)sa * 64 + fl * 4];
            a0 += unpackbf2(ua.x); a1 += unpackbf2(ua.y);
            a2 += unpackbf2(ua.z); a3 += unpackbf2(ua.w);
        }
    }
    // self-loop term on slot 0
    if (g == 0) {
        uint4 un = *(const uint4*)&hsb[(size_t)n * 64 + fl * 4];
        b0 += unpackbf2(un.x); b1 += unpackbf2(un.y);
        b2 += unpackbf2(un.z); b3 += unpackbf2(un.w);
    }
    a0 += b0; a1 += b1; a2 += b2; a3 += b3;
    // combine the 4 slots: xor-16, xor-32
#pragma unroll
    for (int off = 16; off <= 32; off <<= 1) {
        a0.x += __shfl_xor(a0.x, off, 64); a0.y += __shfl_xor(a0.y, off, 64);
        a1.x += __shfl_xor(a1.x, off, 64); a1.y += __shfl_xor(a1.y, off, 64);
        a2.x += __shfl_xor(a2.x, off, 64); a2.y += __shfl_xor(a2.y, off, 64);
        a3.x += __shfl_xor(a3.x, off, 64); a3.y += __shfl_xor(a3.y, off, 64);
    }
    if (g == 0) {
        float di = dinv[n];
        int f = fl * 8;
        float4 bi0 = *(const float4*)&bias[f];
        float4 bi1 = *(const float4*)&bias[f + 4];
        float4 r0 = make_float4(a0.x * di + bi0.x, a0.y * di + bi0.y,
                                a1.x * di + bi0.z, a1.y * di + bi0.w);
        float4 r1 = make_float4(a2.x * di + bi1.x, a2.y * di + bi1.y,
                                a3.x * di + bi1.z, a3.y * di + bi1.w);
        *(float4*)&zout[(size_t)n * 128 + f] = r0;
        *(float4*)&zout[(size_t)n * 128 + f + 4] = r1;
    }
}

// ---------------- BatchNorm stats ----------------
__global__ __launch_bounds__(256) void bnstats_k(const float* __restrict__ z,
                                                 float* __restrict__ sums,
                                                 float* __restrict__ sumsq) {
    __shared__ float ls[128], lq[128];
    int f = threadIdx.x & 127;
    int sub = threadIdx.x >> 7;
    float s = 0.f, q = 0.f;
    for (int r = blockIdx.x * 2 + sub; r < NN; r += gridDim.x * 2) {
        float v = z[(size_t)r * 128 + f];
        s += v;
        q += v * v;
    }
    if (sub) { ls[f] = s; lq[f] = q; }
    __syncthreads();
    if (!sub) {
        atomicAdd(&sums[f], s + ls[f]);
        atomicAdd(&sumsq[f], q + lq[f]);
    }
}

__global__ void bnfinal_k(const float* __restrict__ sums, const float* __restrict__ sumsq,
                          const float* __restrict__ gamma, const float* __restrict__ beta,
                          float* __restrict__ bnA, float* __restrict__ bnC) {
    int f = threadIdx.x;
    if (f < 128) {
        float mean = sums[f] * (1.0f / NN);
        float var = sumsq[f] * (1.0f / NN) - mean * mean;
        float a = gamma[f] * rsqrtf(var + BN_EPS);
        bnA[f] = a;
        bnC[f] = beta[f] - mean * a;
    }
}

// ---------------- edge head (dst-grouped over CSR) ----------------
// Wave per node; unroll 2 (low SGPR pressure) with software-pipelined P gathers.
__global__ __launch_bounds__(256) void edgehead_k(const unsigned int* __restrict__ Pb,
                                                  const float* __restrict__ Q,
                                                  const float* __restrict__ ea,
                                                  const int* __restrict__ offsets,
                                                  const int* __restrict__ counts,
                                                  const int* __restrict__ srcs,
                                                  const int* __restrict__ eids,
                                                  const float* __restrict__ We,   // [16][128]
                                                  const float* __restrict__ bm1,
                                                  const float* __restrict__ Wm2,
                                                  const float* __restrict__ bm2,
                                                  float* __restrict__ out) {
    int lane = threadIdx.x & 63;
    int n = __builtin_amdgcn_readfirstlane(blockIdx.x * 4 + (threadIdx.x >> 6));
    if (n >= NN) return;
    int beg = offsets[n];   // uniform
    int cnt = counts[n];    // uniform
    if (cnt == 0) return;
    const int* ss = srcs + beg;
    const int* es = eids + beg;
    int f = lane * 2;
    v2f wreg[16];
#pragma unroll
    for (int k = 0; k < 16; k++) {
        float2 w = *(const float2*)&We[k * 128 + f];
        wreg[k].x = w.x; wreg[k].y = w.y;
    }
    float2 qv = *(const float2*)&Q[(size_t)n * 128 + f];
    float2 bv = *(const float2*)&bm1[f];
    float2 wv = *(const float2*)&Wm2[f];
    float bm2v = bm2[0];
    v2f qb;
    qb.x = qv.x + bv.x;
    qb.y = qv.y + bv.y;

    // pipelined prologue (reads past cnt are padded/valid; results discarded)
    unsigned int u0 = Pb[(size_t)ss[0] * 64 + lane];
    unsigned int u1 = Pb[(size_t)ss[1] * 64 + lane];
    int t = 0;
    for (; t + 2 <= cnt; t += 2) {
        unsigned int v0n = Pb[(size_t)ss[t + 2] * 64 + lane];   // prefetch next pair
        unsigned int v1n = Pb[(size_t)ss[t + 3] * 64 + lane];
        int e0 = es[t];
        int e1 = es[t + 1];
        const float* ea0 = ea + (size_t)e0 * 16;   // uniform -> s_load
        const float* ea1 = ea + (size_t)e1 * 16;
        v2f a0 = qb + unpackbf2(u0);
        v2f a1 = qb + unpackbf2(u1);
#pragma unroll
        for (int k = 0; k < 16; k++) {
            a0 += wreg[k] * ea0[k];
            a1 += wreg[k] * ea1[k];
        }
        float v0 = fmaxf(a0.x, 0.f) * wv.x + fmaxf(a0.y, 0.f) * wv.y;
        float v1 = fmaxf(a1.x, 0.f) * wv.x + fmaxf(a1.y, 0.f) * wv.y;
#pragma unroll
        for (int off = 32; off; off >>= 1) {
            v0 += __shfl_xor(v0, off, 64);
            v1 += __shfl_xor(v1, off, 64);
        }
        if (lane == 0) {
            out[e0] = v0 + bm2v;
            out[e1] = v1 + bm2v;
        }
        u0 = v0n;
        u1 = v1n;
    }
    if (t < cnt) {  // odd tail; u0 already holds row for ss[t]
        int e0 = es[t];
        const float* ea0 = ea + (size_t)e0 * 16;
        v2f a0 = qb + unpackbf2(u0);
#pragma unroll
        for (int k = 0; k < 16; k++) a0 += wreg[k] * ea0[k];
        float v0 = fmaxf(a0.x, 0.f) * wv.x + fmaxf(a0.y, 0.f) * wv.y;
#pragma unroll
        for (int off = 32; off; off >>= 1) v0 += __shfl_xor(v0, off, 64);
        if (lane == 0) out[e0] = v0 + bm2v;
    }
}

// ---------------- launcher ----------------
extern "C" void kernel_launch(void* const* d_in, const int* in_sizes, int n_in,
                              void* d_out, int out_size, void* d_ws, size_t ws_size,
                              hipStream_t stream) {
    const float* x     = (const float*)d_in[0];
    const int*   ei    = (const int*)d_in[1];
    const float* ea    = (const float*)d_in[2];
    const float* W1    = (const float*)d_in[3];
    const float* b1    = (const float*)d_in[4];
    const float* gamma = (const float*)d_in[5];
    const float* beta  = (const float*)d_in[6];
    const float* W2    = (const float*)d_in[7];
    const float* b2    = (const float*)d_in[8];
    const float* Wm1   = (const float*)d_in[9];
    const float* bm1   = (const float*)d_in[10];
    const float* Wm2   = (const float*)d_in[11];
    const float* bm2   = (const float*)d_in[12];
    float* out = (float*)d_out;

    const int* srcI = ei;
    const int* dstI = ei + NE;

    char* w = (char*)d_ws;
    auto alloc = [&](size_t bytes) {
        char* p = w;
        w += (bytes + 255) & ~(size_t)255;
        return p;
    };
    float* dinv    = (float*)alloc(NN * 4);
    int*   counts  = (int*)alloc(NN * 4);
    int*   offsets = (int*)alloc(NN * 4);
    int*   cursor  = (int*)alloc(NN * 4);
    int*   srcs    = (int*)alloc((size_t)(NE + 8) * 4);
    int*   eids    = (int*)alloc((size_t)(NE + 8) * 4);
    float* sums    = (float*)alloc(128 * 4);
    float* sumsq   = (float*)alloc(128 * 4);
    float* bnA     = (float*)alloc(128 * 4);
    float* bnC     = (float*)alloc(128 * 4);
    unsigned int* hsb = (unsigned int*)alloc((size_t)NN * 64 * 4);
    float* bufZ    = (float*)alloc((size_t)NN * 128 * 4);

    hipMemsetAsync(counts, 0, NN * 4, stream);
    hipMemsetAsync(sums, 0, 128 * 4, stream);
    hipMemsetAsync(sumsq, 0, 128 * 4, stream);

    hist_k<<<(NE + 255) / 256, 256, 0, stream>>>(dstI, counts);
    dinv_k<<<(NN + 255) / 256, 256, 0, stream>>>(counts, dinv);
    scan_k<<<1, 1024, 0, stream>>>(counts, offsets, cursor);
    fill_k<<<(NE + 255) / 256, 256, 0, stream>>>(srcI, dstI, cursor, srcs, eids);

    const int GB = (NN + 63) / 64;
    const int AGG = (NN + 3) / 4;

    // conv1
    gemm128<<<GB, 256, 0, stream>>>(x, W1, nullptr, hsb, dinv, nullptr, nullptr, NN);
    aggregate_k<<<AGG, 256, 0, stream>>>(hsb, offsets, counts, srcs, dinv, b1, bufZ);

    // BN stats (apply fused into conv2 A-staging)
    bnstats_k<<<256, 256, 0, stream>>>(bufZ, sums, sumsq);
    bnfinal_k<<<1, 128, 0, stream>>>(sums, sumsq, gamma, beta, bnA, bnC);

    // conv2
    gemm128<<<GB, 256, 0, stream>>>(bufZ, W2, nullptr, hsb, dinv, bnA, bnC, NN);
    aggregate_k<<<AGG, 256, 0, stream>>>(hsb, offsets, counts, srcs, dinv, b2, bufZ);

    // edge head precompute: P -> bf16 (hsb reused); Q -> bufZ in-place
    gemm128<<<GB, 256, 0, stream>>>(bufZ, Wm1, nullptr, hsb, nullptr, nullptr, nullptr, NN);
    gemm128<<<GB, 256, 0, stream>>>(bufZ, Wm1 + 128 * 128, bufZ, nullptr, nullptr, nullptr, nullptr, NN);

    edgehead_k<<<AGG, 256, 0, stream>>>(hsb, bufZ, ea, offsets, counts, srcs, eids,
                                        Wm1 + 256 * 128, bm1, Wm2, bm2, out);
}

// Round 6
// 616.177 us; speedup vs baseline: 1.0749x; 1.0749x over previous
//
#include <hip/hip_runtime.h>
#include <hip/hip_bf16.h>

#define NN 50000
#define NE 800000
#define H 128
#define DE 16
#define BN_EPS 1e-5f

typedef float v2f __attribute__((ext_vector_type(2)));
typedef float v4f __attribute__((ext_vector_type(4)));
typedef short bfrag __attribute__((ext_vector_type(8)));   // 8 bf16 = 4 VGPRs

__device__ __forceinline__ unsigned int packbf2(float a, float b) {
    __hip_bfloat162 h = __float22bfloat162_rn(make_float2(a, b));
    return *(unsigned int*)&h;
}
__device__ __forceinline__ v2f unpackbf2(unsigned int u) {
    v2f r;
    r.x = __uint_as_float(u << 16);
    r.y = __uint_as_float(u & 0xffff0000u);
    return r;
}
__device__ __forceinline__ bfrag cvt8(float4 a0, float4 a1) {
    union { uint4 u; bfrag f; } x;
    x.u.x = packbf2(a0.x, a0.y);
    x.u.y = packbf2(a0.z, a0.w);
    x.u.z = packbf2(a1.x, a1.y);
    x.u.w = packbf2(a1.z, a1.w);
    return x.f;
}

// ---------------- CSR build ----------------
__global__ void hist_k(const int* __restrict__ dst, int* __restrict__ counts) {
    int e = blockIdx.x * 256 + threadIdx.x;
    if (e < NE) atomicAdd(&counts[dst[e]], 1);
}

__global__ void dinv_k(const int* __restrict__ counts, float* __restrict__ dinv) {
    int i = blockIdx.x * 256 + threadIdx.x;
    if (i < NN) dinv[i] = rsqrtf((float)counts[i] + 1.0f);
}

__global__ __launch_bounds__(1024) void scan_k(const int* __restrict__ counts,
                                               int* __restrict__ offsets,
                                               int* __restrict__ cursor) {
    __shared__ int part[1024];
    int t = threadIdx.x;
    const int CH = (NN + 1023) / 1024;  // 49
    int lo = t * CH, hi = min(lo + CH, NN);
    int s = 0;
    for (int i = lo; i < hi; i++) s += counts[i];
    part[t] = s;
    __syncthreads();
    for (int off = 1; off < 1024; off <<= 1) {
        int v = 0;
        if (t >= off) v = part[t - off];
        __syncthreads();
        part[t] += v;
        __syncthreads();
    }
    int run = part[t] - s;  // exclusive prefix
    for (int i = lo; i < hi; i++) {
        offsets[i] = run;
        cursor[i]  = run;
        run += counts[i];
    }
}

// CSR payload: (src, original edge id)
__global__ void fill_k(const int* __restrict__ src, const int* __restrict__ dst,
                       int* __restrict__ cursor, int2* __restrict__ pairs) {
    int e = blockIdx.x * 256 + threadIdx.x;
    if (e < NE) {
        int pos = atomicAdd(&cursor[dst[e]], 1);
        pairs[pos] = make_int2(src[e], e);
    }
}

// ---------------- B preconvert: Bt[n][k] = bf16(B[k][n]) ----------------
__global__ void cvtB_k(const float* __restrict__ s0, const float* __restrict__ s1,
                       const float* __restrict__ s2, const float* __restrict__ s3,
                       short* __restrict__ d0, short* __restrict__ d1,
                       short* __restrict__ d2, short* __restrict__ d3) {
    const float* s = blockIdx.y == 0 ? s0 : blockIdx.y == 1 ? s1 : blockIdx.y == 2 ? s2 : s3;
    short* d = blockIdx.y == 0 ? d0 : blockIdx.y == 1 ? d1 : blockIdx.y == 2 ? d2 : d3;
    int idx = blockIdx.x * 256 + threadIdx.x;   // 16384
    int n = idx & 127, k = idx >> 7;
    float v = s[k * 128 + n];                   // coalesced read
    d[n * 128 + k] = (short)(packbf2(v, v) & 0xffff);
}

// ---------------- MFMA GEMM: C[M x 128] = A'[M x 128] @ B[128 x 128] ----------------
// Bt is bf16 [n][k] (pre-transposed). A fp32, cvt'd in-register; optional per-column
// BN+ReLU transform (tA/tC), optional per-row scale. Output fp32 C or bf16-packed Cb.
// No LDS, no barriers. 4 waves/block, wave w -> rows [blk*64 + w*16, +16).
__global__ __launch_bounds__(256) void gemm_mfma(const float* __restrict__ A,
                                                 const short* __restrict__ Bt,
                                                 float* __restrict__ C,
                                                 unsigned int* __restrict__ Cb,
                                                 const float* __restrict__ rowScale,
                                                 const float* __restrict__ tA,
                                                 const float* __restrict__ tC,
                                                 int M) {
    int lane = threadIdx.x & 63;
    int w = threadIdx.x >> 6;
    int i = lane & 15;      // A row-in-tile / B col-in-tile
    int q = lane >> 4;      // quad: k chunk q*8..q*8+7
    int r0 = blockIdx.x * 64 + w * 16;
    int arow = min(r0 + i, M - 1);
    const float* Arow = A + (size_t)arow * 128;

    v4f acc[8];
#pragma unroll
    for (int c = 0; c < 8; c++) acc[c] = (v4f)0.f;

#pragma unroll
    for (int kc = 0; kc < 128; kc += 32) {
        int kb = kc + q * 8;
        float4 a0 = *(const float4*)&Arow[kb];
        float4 a1 = *(const float4*)&Arow[kb + 4];
        if (tA) {
            float4 t0 = *(const float4*)&tA[kb];
            float4 t1 = *(const float4*)&tA[kb + 4];
            float4 c0 = *(const float4*)&tC[kb];
            float4 c1 = *(const float4*)&tC[kb + 4];
            a0.x = fmaxf(a0.x * t0.x + c0.x, 0.f);
            a0.y = fmaxf(a0.y * t0.y + c0.y, 0.f);
            a0.z = fmaxf(a0.z * t0.z + c0.z, 0.f);
            a0.w = fmaxf(a0.w * t0.w + c0.w, 0.f);
            a1.x = fmaxf(a1.x * t1.x + c1.x, 0.f);
            a1.y = fmaxf(a1.y * t1.y + c1.y, 0.f);
            a1.z = fmaxf(a1.z * t1.z + c1.z, 0.f);
            a1.w = fmaxf(a1.w * t1.w + c1.w, 0.f);
        }
        bfrag af = cvt8(a0, a1);
#pragma unroll
        for (int c = 0; c < 8; c++) {
            bfrag bf = *(const bfrag*)&Bt[(size_t)(c * 16 + i) * 128 + kb];  // 16B aligned, L1-resident
            acc[c] = __builtin_amdgcn_mfma_f32_16x16x32_bf16(af, bf, acc[c], 0, 0, 0);
        }
    }

    // epilogue: D row = r0 + q*4 + reg, col = c*16 + i
    int orow0 = r0 + q * 4;
    v4f ds = (v4f)1.f;
    if (rowScale) ds = *(const v4f*)&rowScale[min(orow0, M - 4)];
    if (Cb) {
#pragma unroll
        for (int c = 0; c < 8; c++) {
            int col = c * 16 + i;
#pragma unroll
            for (int r = 0; r < 4; r++) {
                float v = acc[c][r] * ds[r];
                float vp = __shfl_xor(v, 1, 64);   // partner col (i^1)
                if (!(i & 1) && orow0 + r < M)
                    Cb[(size_t)(orow0 + r) * 64 + (col >> 1)] = packbf2(v, vp);
            }
        }
    } else {
#pragma unroll
        for (int c = 0; c < 8; c++) {
            int col = c * 16 + i;
#pragma unroll
            for (int r = 0; r < 4; r++) {
                if (orow0 + r < M)
                    C[(size_t)(orow0 + r) * 128 + col] = acc[c][r] * ds[r];
            }
        }
    }
}

// ---------------- aggregation: z[n] = dinv[n]*(sum_{e->n} hs[src] + hs[n]) + b ----------------
// hs bf16-packed. Wave per node; uniform scalar index loads; 4 gathers in flight. (R2 best)
__global__ __launch_bounds__(256) void aggregate_k(const unsigned int* __restrict__ hsb,
                                                   const int* __restrict__ offsets,
                                                   const int* __restrict__ counts,
                                                   const int2* __restrict__ pairs,
                                                   const float* __restrict__ dinv,
                                                   const float* __restrict__ bias,
                                                   float* __restrict__ zout) {
    int lane = threadIdx.x & 63;
    int n = __builtin_amdgcn_readfirstlane(blockIdx.x * 4 + (threadIdx.x >> 6));
    if (n >= NN) return;
    int beg = offsets[n];
    int cnt = counts[n];
    const int2* lst = pairs + beg;
    v2f a0 = {0.f, 0.f}, a1 = {0.f, 0.f}, a2 = {0.f, 0.f}, a3 = {0.f, 0.f};
    int t = 0;
    for (; t + 4 <= cnt; t += 4) {
        int s0 = lst[t].x;
        int s1 = lst[t + 1].x;
        int s2 = lst[t + 2].x;
        int s3 = lst[t + 3].x;
        unsigned int u0 = hsb[(size_t)s0 * 64 + lane];
        unsigned int u1 = hsb[(size_t)s1 * 64 + lane];
        unsigned int u2 = hsb[(size_t)s2 * 64 + lane];
        unsigned int u3 = hsb[(size_t)s3 * 64 + lane];
        a0 += unpackbf2(u0);
        a1 += unpackbf2(u1);
        a2 += unpackbf2(u2);
        a3 += unpackbf2(u3);
    }
    for (; t < cnt; t++) {
        int s0 = lst[t].x;
        a0 += unpackbf2(hsb[(size_t)s0 * 64 + lane]);
    }
    v2f self = unpackbf2(hsb[(size_t)n * 64 + lane]);
    float di = dinv[n];
    int f = lane * 2;
    float2 b = *(const float2*)&bias[f];
    v2f sum = (a0 + a1) + (a2 + a3) + self;
    float2 r;
    r.x = sum.x * di + b.x;
    r.y = sum.y * di + b.y;
    *(float2*)&zout[(size_t)n * 128 + f] = r;
}

// ---------------- BatchNorm stats ----------------
__global__ __launch_bounds__(256) void bnstats_k(const float* __restrict__ z,
                                                 float* __restrict__ sums,
                                                 float* __restrict__ sumsq) {
    __shared__ float ls[128], lq[128];
    int f = threadIdx.x & 127;
    int sub = threadIdx.x >> 7;
    float s = 0.f, q = 0.f;
    for (int r = blockIdx.x * 2 + sub; r < NN; r += gridDim.x * 2) {
        float v = z[(size_t)r * 128 + f];
        s += v;
        q += v * v;
    }
    if (sub) { ls[f] = s; lq[f] = q; }
    __syncthreads();
    if (!sub) {
        atomicAdd(&sums[f], s + ls[f]);
        atomicAdd(&sumsq[f], q + lq[f]);
    }
}

__global__ void bnfinal_k(const float* __restrict__ sums, const float* __restrict__ sumsq,
                          const float* __restrict__ gamma, const float* __restrict__ beta,
                          float* __restrict__ bnA, float* __restrict__ bnC) {
    int f = threadIdx.x;
    if (f < 128) {
        float mean = sums[f] * (1.0f / NN);
        float var = sumsq[f] * (1.0f / NN) - mean * mean;
        float a = gamma[f] * rsqrtf(var + BN_EPS);
        bnA[f] = a;
        bnC[f] = beta[f] - mean * a;
    }
}

// ---------------- edge head (dst-grouped over CSR) ---------------- (R2 best)
__global__ __launch_bounds__(256) void edgehead_k(const unsigned int* __restrict__ Pb,
                                                  const float* __restrict__ Q,
                                                  const float* __restrict__ ea,
                                                  const int* __restrict__ offsets,
                                                  const int* __restrict__ counts,
                                                  const int2* __restrict__ pairs,
                                                  const float* __restrict__ We,   // [16][128]
                                                  const float* __restrict__ bm1,
                                                  const float* __restrict__ Wm2,
                                                  const float* __restrict__ bm2,
                                                  float* __restrict__ out) {
    int lane = threadIdx.x & 63;
    int n = __builtin_amdgcn_readfirstlane(blockIdx.x * 4 + (threadIdx.x >> 6));
    if (n >= NN) return;
    int beg = offsets[n];
    int cnt = counts[n];
    if (cnt == 0) return;
    const int2* lst = pairs + beg;
    int f = lane * 2;
    v2f wreg[16];
#pragma unroll
    for (int k = 0; k < 16; k++) {
        float2 w = *(const float2*)&We[k * 128 + f];
        wreg[k].x = w.x; wreg[k].y = w.y;
    }
    float2 qv = *(const float2*)&Q[(size_t)n * 128 + f];
    float2 bv = *(const float2*)&bm1[f];
    float2 wv = *(const float2*)&Wm2[f];
    float bm2v = bm2[0];
    v2f qb;
    qb.x = qv.x + bv.x;
    qb.y = qv.y + bv.y;

    int t = 0;
    for (; t + 2 <= cnt; t += 2) {
        int2 pr0 = lst[t];
        int2 pr1 = lst[t + 1];
        unsigned int u0 = Pb[(size_t)pr0.x * 64 + lane];
        unsigned int u1 = Pb[(size_t)pr1.x * 64 + lane];
        const float* ea0 = ea + (size_t)pr0.y * 16;
        const float* ea1 = ea + (size_t)pr1.y * 16;
        v2f a0 = qb + unpackbf2(u0);
        v2f a1 = qb + unpackbf2(u1);
#pragma unroll
        for (int k = 0; k < 16; k++) {
            a0 += wreg[k] * ea0[k];
            a1 += wreg[k] * ea1[k];
        }
        float v0 = fmaxf(a0.x, 0.f) * wv.x + fmaxf(a0.y, 0.f) * wv.y;
        float v1 = fmaxf(a1.x, 0.f) * wv.x + fmaxf(a1.y, 0.f) * wv.y;
#pragma unroll
        for (int off = 32; off; off >>= 1) {
            v0 += __shfl_xor(v0, off, 64);
            v1 += __shfl_xor(v1, off, 64);
        }
        if (lane == 0) {
            out[pr0.y] = v0 + bm2v;
            out[pr1.y] = v1 + bm2v;
        }
    }
    if (t < cnt) {
        int2 pr0 = lst[t];
        unsigned int u0 = Pb[(size_t)pr0.x * 64 + lane];
        const float* ea0 = ea + (size_t)pr0.y * 16;
        v2f a0 = qb + unpackbf2(u0);
#pragma unroll
        for (int k = 0; k < 16; k++) a0 += wreg[k] * ea0[k];
        float v0 = fmaxf(a0.x, 0.f) * wv.x + fmaxf(a0.y, 0.f) * wv.y;
#pragma unroll
        for (int off = 32; off; off >>= 1) v0 += __shfl_xor(v0, off, 64);
        if (lane == 0) out[pr0.y] = v0 + bm2v;
    }
}

// ---------------- launcher ----------------
extern "C" void kernel_launch(void* const* d_in, const int* in_sizes, int n_in,
                              void* d_out, int out_size, void* d_ws, size_t ws_size,
                              hipStream_t stream) {
    const float* x     = (const float*)d_in[0];
    const int*   ei    = (const int*)d_in[1];
    const float* ea    = (const float*)d_in[2];
    const float* W1    = (const float*)d_in[3];
    const float* b1    = (const float*)d_in[4];
    const float* gamma = (const float*)d_in[5];
    const float* beta  = (const float*)d_in[6];
    const float* W2    = (const float*)d_in[7];
    const float* b2    = (const float*)d_in[8];
    const float* Wm1   = (const float*)d_in[9];
    const float* bm1   = (const float*)d_in[10];
    const float* Wm2   = (const float*)d_in[11];
    const float* bm2   = (const float*)d_in[12];
    float* out = (float*)d_out;

    const int* srcI = ei;
    const int* dstI = ei + NE;

    char* w = (char*)d_ws;
    auto alloc = [&](size_t bytes) {
        char* p = w;
        w += (bytes + 255) & ~(size_t)255;
        return p;
    };
    float* dinv    = (float*)alloc(NN * 4);
    int*   counts  = (int*)alloc(NN * 4);
    int*   offsets = (int*)alloc(NN * 4);
    int*   cursor  = (int*)alloc(NN * 4);
    int2*  pairs   = (int2*)alloc((size_t)NE * 8);
    float* sums    = (float*)alloc(128 * 4);
    float* sumsq   = (float*)alloc(128 * 4);
    float* bnA     = (float*)alloc(128 * 4);
    float* bnC     = (float*)alloc(128 * 4);
    short* bt1     = (short*)alloc(128 * 128 * 2);
    short* bt2     = (short*)alloc(128 * 128 * 2);
    short* bts     = (short*)alloc(128 * 128 * 2);
    short* btd     = (short*)alloc(128 * 128 * 2);
    unsigned int* hsb = (unsigned int*)alloc((size_t)NN * 64 * 4);
    float* bufZ    = (float*)alloc((size_t)NN * 128 * 4);

    hipMemsetAsync(counts, 0, NN * 4, stream);
    hipMemsetAsync(sums, 0, 128 * 4, stream);
    hipMemsetAsync(sumsq, 0, 128 * 4, stream);

    hist_k<<<(NE + 255) / 256, 256, 0, stream>>>(dstI, counts);
    dinv_k<<<(NN + 255) / 256, 256, 0, stream>>>(counts, dinv);
    scan_k<<<1, 1024, 0, stream>>>(counts, offsets, cursor);
    fill_k<<<(NE + 255) / 256, 256, 0, stream>>>(srcI, dstI, cursor, pairs);
    cvtB_k<<<dim3(64, 4), 256, 0, stream>>>(W1, W2, Wm1, Wm1 + 128 * 128,
                                            bt1, bt2, bts, btd);

    const int GB = (NN + 63) / 64;   // 782
    const int AGG = (NN + 3) / 4;

    // conv1: hs1 = (x@W1)*dinv -> bf16 ; z1 -> bufZ
    gemm_mfma<<<GB, 256, 0, stream>>>(x, bt1, nullptr, hsb, dinv, nullptr, nullptr, NN);
    aggregate_k<<<AGG, 256, 0, stream>>>(hsb, offsets, counts, pairs, dinv, b1, bufZ);

    // BN stats (apply fused into conv2 A-frag load)
    bnstats_k<<<256, 256, 0, stream>>>(bufZ, sums, sumsq);
    bnfinal_k<<<1, 128, 0, stream>>>(sums, sumsq, gamma, beta, bnA, bnC);

    // conv2: hs2 = (relu(bn(z1))@W2)*dinv -> bf16 ; z2 -> bufZ
    gemm_mfma<<<GB, 256, 0, stream>>>(bufZ, bt2, nullptr, hsb, dinv, bnA, bnC, NN);
    aggregate_k<<<AGG, 256, 0, stream>>>(hsb, offsets, counts, pairs, dinv, b2, bufZ);

    // edge head precompute: P = z2@Ws -> bf16 (hsb reused); Q = z2@Wd -> bufZ in-place
    gemm_mfma<<<GB, 256, 0, stream>>>(bufZ, bts, nullptr, hsb, nullptr, nullptr, nullptr, NN);
    gemm_mfma<<<GB, 256, 0, stream>>>(bufZ, btd, bufZ, nullptr, nullptr, nullptr, nullptr, NN);

    edgehead_k<<<AGG, 256, 0, stream>>>(hsb, bufZ, ea, offsets, counts, pairs,
                                        Wm1 + 256 * 128, bm1, Wm2, bm2, out);
}

// Round 7
// 525.460 us; speedup vs baseline: 1.2604x; 1.1726x over previous
//
#include <hip/hip_runtime.h>
#include <hip/hip_bf16.h>

#define NN 50000
#define NE 800000
#define H 128
#define DE 16
#define BN_EPS 1e-5f
#define NB_SCAN 196   // ceil(50000/256)

typedef float v2f __attribute__((ext_vector_type(2)));
typedef float v4f __attribute__((ext_vector_type(4)));
typedef short bfrag __attribute__((ext_vector_type(8)));   // 8 bf16 = 4 VGPRs

__device__ __forceinline__ unsigned int packbf2(float a, float b) {
    __hip_bfloat162 h = __float22bfloat162_rn(make_float2(a, b));
    return *(unsigned int*)&h;
}
__device__ __forceinline__ v2f unpackbf2(unsigned int u) {
    v2f r;
    r.x = __uint_as_float(u << 16);
    r.y = __uint_as_float(u & 0xffff0000u);
    return r;
}
__device__ __forceinline__ bfrag cvt8(float4 a0, float4 a1) {
    union { uint4 u; bfrag f; } x;
    x.u.x = packbf2(a0.x, a0.y);
    x.u.y = packbf2(a0.z, a0.w);
    x.u.z = packbf2(a1.x, a1.y);
    x.u.w = packbf2(a1.z, a1.w);
    return x.f;
}

// ---------------- CSR build ----------------
__global__ void hist_k(const int* __restrict__ dst, int* __restrict__ counts) {
    int e = blockIdx.x * 256 + threadIdx.x;
    if (e < NE) atomicAdd(&counts[dst[e]], 1);
}

// hierarchical coalesced scan (3 phases); dinv folded into phase 3
__global__ void scan1_k(const int* __restrict__ counts, int* __restrict__ bsum) {
    __shared__ int sh[256];
    int i = blockIdx.x * 256 + threadIdx.x;
    int v = (i < NN) ? counts[i] : 0;
    sh[threadIdx.x] = v;
    __syncthreads();
    for (int off = 128; off; off >>= 1) {
        if (threadIdx.x < off) sh[threadIdx.x] += sh[threadIdx.x + off];
        __syncthreads();
    }
    if (!threadIdx.x) bsum[blockIdx.x] = sh[0];
}

__global__ void scan2_k(int* __restrict__ bsum) {
    __shared__ int sh[256];
    int t = threadIdx.x;
    int v = (t < NB_SCAN) ? bsum[t] : 0;
    sh[t] = v;
    __syncthreads();
    for (int off = 1; off < 256; off <<= 1) {
        int x = (t >= off) ? sh[t - off] : 0;
        __syncthreads();
        sh[t] += x;
        __syncthreads();
    }
    if (t < NB_SCAN) bsum[t] = sh[t] - v;  // exclusive
}

__global__ void scan3_k(const int* __restrict__ counts, const int* __restrict__ bsum,
                        int* __restrict__ offsets, int* __restrict__ cursor,
                        float* __restrict__ dinv) {
    __shared__ int sh[256];
    int i = blockIdx.x * 256 + threadIdx.x;
    int v = (i < NN) ? counts[i] : 0;
    sh[threadIdx.x] = v;
    __syncthreads();
    for (int off = 1; off < 256; off <<= 1) {
        int x = (threadIdx.x >= off) ? sh[threadIdx.x - off] : 0;
        __syncthreads();
        sh[threadIdx.x] += x;
        __syncthreads();
    }
    if (i < NN) {
        int excl = sh[threadIdx.x] - v + bsum[blockIdx.x];
        offsets[i] = excl;
        cursor[i] = excl;
        dinv[i] = rsqrtf((float)v + 1.0f);
    }
}

// CSR payload: (src, original edge id); pad 64 entries so 64-wide vector loads are safe
__global__ void fill_k(const int* __restrict__ src, const int* __restrict__ dst,
                       int* __restrict__ cursor, int2* __restrict__ pairs) {
    int e = blockIdx.x * 256 + threadIdx.x;
    if (e < NE) {
        int pos = atomicAdd(&cursor[dst[e]], 1);
        pairs[pos] = make_int2(src[e], e);
        if (e < 64) pairs[NE + e] = make_int2(0, 0);
    }
}

// ---------------- B preconvert: Bt[n][k] = bf16(B[k][n]) ----------------
__global__ void cvtB_k(const float* __restrict__ s0, const float* __restrict__ s1,
                       const float* __restrict__ s2, const float* __restrict__ s3,
                       short* __restrict__ d0, short* __restrict__ d1,
                       short* __restrict__ d2, short* __restrict__ d3) {
    const float* s = blockIdx.y == 0 ? s0 : blockIdx.y == 1 ? s1 : blockIdx.y == 2 ? s2 : s3;
    short* d = blockIdx.y == 0 ? d0 : blockIdx.y == 1 ? d1 : blockIdx.y == 2 ? d2 : d3;
    int idx = blockIdx.x * 256 + threadIdx.x;   // 16384
    int n = idx & 127, k = idx >> 7;
    float v = s[k * 128 + n];
    d[n * 128 + k] = (short)(packbf2(v, v) & 0xffff);
}

// ---------------- MFMA GEMM: C[M x 128] = A'[M x 128] @ B[128 x 128] ----------------
__global__ __launch_bounds__(256) void gemm_mfma(const float* __restrict__ A,
                                                 const short* __restrict__ Bt,
                                                 float* __restrict__ C,
                                                 unsigned int* __restrict__ Cb,
                                                 const float* __restrict__ rowScale,
                                                 const float* __restrict__ tA,
                                                 const float* __restrict__ tC,
                                                 int M) {
    int lane = threadIdx.x & 63;
    int w = threadIdx.x >> 6;
    int i = lane & 15;
    int q = lane >> 4;
    int r0 = blockIdx.x * 64 + w * 16;
    int arow = min(r0 + i, M - 1);
    const float* Arow = A + (size_t)arow * 128;

    v4f acc[8];
#pragma unroll
    for (int c = 0; c < 8; c++) acc[c] = (v4f)0.f;

#pragma unroll
    for (int kc = 0; kc < 128; kc += 32) {
        int kb = kc + q * 8;
        float4 a0 = *(const float4*)&Arow[kb];
        float4 a1 = *(const float4*)&Arow[kb + 4];
        if (tA) {
            float4 t0 = *(const float4*)&tA[kb];
            float4 t1 = *(const float4*)&tA[kb + 4];
            float4 c0 = *(const float4*)&tC[kb];
            float4 c1 = *(const float4*)&tC[kb + 4];
            a0.x = fmaxf(a0.x * t0.x + c0.x, 0.f);
            a0.y = fmaxf(a0.y * t0.y + c0.y, 0.f);
            a0.z = fmaxf(a0.z * t0.z + c0.z, 0.f);
            a0.w = fmaxf(a0.w * t0.w + c0.w, 0.f);
            a1.x = fmaxf(a1.x * t1.x + c1.x, 0.f);
            a1.y = fmaxf(a1.y * t1.y + c1.y, 0.f);
            a1.z = fmaxf(a1.z * t1.z + c1.z, 0.f);
            a1.w = fmaxf(a1.w * t1.w + c1.w, 0.f);
        }
        bfrag af = cvt8(a0, a1);
#pragma unroll
        for (int c = 0; c < 8; c++) {
            bfrag bf = *(const bfrag*)&Bt[(size_t)(c * 16 + i) * 128 + kb];
            acc[c] = __builtin_amdgcn_mfma_f32_16x16x32_bf16(af, bf, acc[c], 0, 0, 0);
        }
    }

    int orow0 = r0 + q * 4;
    v4f ds = (v4f)1.f;
    if (rowScale) ds = *(const v4f*)&rowScale[min(orow0, M - 4)];
    if (Cb) {
#pragma unroll
        for (int c = 0; c < 8; c++) {
            int col = c * 16 + i;
#pragma unroll
            for (int r = 0; r < 4; r++) {
                float v = acc[c][r] * ds[r];
                float vp = __shfl_xor(v, 1, 64);
                if (!(i & 1) && orow0 + r < M)
                    Cb[(size_t)(orow0 + r) * 64 + (col >> 1)] = packbf2(v, vp);
            }
        }
    } else {
#pragma unroll
        for (int c = 0; c < 8; c++) {
            int col = c * 16 + i;
#pragma unroll
            for (int r = 0; r < 4; r++) {
                if (orow0 + r < M)
                    C[(size_t)(orow0 + r) * 128 + col] = acc[c][r] * ds[r];
            }
        }
    }
}

// ---------------- merged P/Q MFMA GEMM: P(bf16)=A@Bs, Q(fp32, in-place ok)=A@Bd ----------
__global__ __launch_bounds__(256) void gemm_pq(const float* __restrict__ A,
                                               const short* __restrict__ Bs_,
                                               const short* __restrict__ Bd_,
                                               unsigned int* __restrict__ Pb,
                                               float* __restrict__ Qout,
                                               int M) {
    int lane = threadIdx.x & 63;
    int w = threadIdx.x >> 6;
    int i = lane & 15;
    int q = lane >> 4;
    int r0 = blockIdx.x * 64 + w * 16;
    int arow = min(r0 + i, M - 1);
    const float* Arow = A + (size_t)arow * 128;

    v4f accP[8], accQ[8];
#pragma unroll
    for (int c = 0; c < 8; c++) { accP[c] = (v4f)0.f; accQ[c] = (v4f)0.f; }

#pragma unroll
    for (int kc = 0; kc < 128; kc += 32) {
        int kb = kc + q * 8;
        float4 a0 = *(const float4*)&Arow[kb];
        float4 a1 = *(const float4*)&Arow[kb + 4];
        bfrag af = cvt8(a0, a1);
#pragma unroll
        for (int c = 0; c < 8; c++) {
            bfrag bs = *(const bfrag*)&Bs_[(size_t)(c * 16 + i) * 128 + kb];
            bfrag bd = *(const bfrag*)&Bd_[(size_t)(c * 16 + i) * 128 + kb];
            accP[c] = __builtin_amdgcn_mfma_f32_16x16x32_bf16(af, bs, accP[c], 0, 0, 0);
            accQ[c] = __builtin_amdgcn_mfma_f32_16x16x32_bf16(af, bd, accQ[c], 0, 0, 0);
        }
    }

    int orow0 = r0 + q * 4;
#pragma unroll
    for (int c = 0; c < 8; c++) {
        int col = c * 16 + i;
#pragma unroll
        for (int r = 0; r < 4; r++) {
            float v = accP[c][r];
            float vp = __shfl_xor(v, 1, 64);
            if (orow0 + r < M) {
                if (!(i & 1))
                    Pb[(size_t)(orow0 + r) * 64 + (col >> 1)] = packbf2(v, vp);
                Qout[(size_t)(orow0 + r) * 128 + col] = accQ[c][r];
            }
        }
    }
}

// ---------------- aggregation: z[n] = dinv[n]*(sum_{e->n} hs[src] + hs[n]) + b ----------------
// Wave per node. Indices arrive via ONE coalesced vector load per 64 edges;
// per-edge index extracted with v_readlane (no scalar-memory chain). 8 gathers in flight.
__global__ __launch_bounds__(256, 8) void aggregate_k(const unsigned int* __restrict__ hsb,
                                                      const int* __restrict__ offsets,
                                                      const int* __restrict__ counts,
                                                      const int2* __restrict__ pairs,
                                                      const float* __restrict__ dinv,
                                                      const float* __restrict__ bias,
                                                      float* __restrict__ zout) {
    int lane = threadIdx.x & 63;
    int n = __builtin_amdgcn_readfirstlane(blockIdx.x * 4 + (threadIdx.x >> 6));
    if (n >= NN) return;
    int beg = offsets[n];
    int cnt = counts[n];
    v2f a0 = {0.f, 0.f}, a1 = {0.f, 0.f}, a2 = {0.f, 0.f}, a3 = {0.f, 0.f};
    v2f a4 = {0.f, 0.f}, a5 = {0.f, 0.f}, a6 = {0.f, 0.f}, a7 = {0.f, 0.f};
    for (int c = 0; c < cnt; c += 64) {
        int vsrc = pairs[beg + c + lane].x;   // one coalesced load covers 64 edges
        int m = min(64, cnt - c);
        int t = 0;
        for (; t + 8 <= m; t += 8) {
            int s0 = __builtin_amdgcn_readlane(vsrc, t);
            int s1 = __builtin_amdgcn_readlane(vsrc, t + 1);
            int s2 = __builtin_amdgcn_readlane(vsrc, t + 2);
            int s3 = __builtin_amdgcn_readlane(vsrc, t + 3);
            int s4 = __builtin_amdgcn_readlane(vsrc, t + 4);
            int s5 = __builtin_amdgcn_readlane(vsrc, t + 5);
            int s6 = __builtin_amdgcn_readlane(vsrc, t + 6);
            int s7 = __builtin_amdgcn_readlane(vsrc, t + 7);
            unsigned int u0 = hsb[(size_t)s0 * 64 + lane];
            unsigned int u1 = hsb[(size_t)s1 * 64 + lane];
            unsigned int u2 = hsb[(size_t)s2 * 64 + lane];
            unsigned int u3 = hsb[(size_t)s3 * 64 + lane];
            unsigned int u4 = hsb[(size_t)s4 * 64 + lane];
            unsigned int u5 = hsb[(size_t)s5 * 64 + lane];
            unsigned int u6 = hsb[(size_t)s6 * 64 + lane];
            unsigned int u7 = hsb[(size_t)s7 * 64 + lane];
            a0 += unpackbf2(u0);
            a1 += unpackbf2(u1);
            a2 += unpackbf2(u2);
            a3 += unpackbf2(u3);
            a4 += unpackbf2(u4);
            a5 += unpackbf2(u5);
            a6 += unpackbf2(u6);
            a7 += unpackbf2(u7);
        }
        for (; t < m; t++) {
            int s0 = __builtin_amdgcn_readlane(vsrc, t);
            a0 += unpackbf2(hsb[(size_t)s0 * 64 + lane]);
        }
    }
    v2f self = unpackbf2(hsb[(size_t)n * 64 + lane]);
    float di = dinv[n];
    int f = lane * 2;
    float2 b = *(const float2*)&bias[f];
    v2f sum = ((a0 + a1) + (a2 + a3)) + ((a4 + a5) + (a6 + a7)) + self;
    float2 r;
    r.x = sum.x * di + b.x;
    r.y = sum.y * di + b.y;
    *(float2*)&zout[(size_t)n * 128 + f] = r;
}

// ---------------- BatchNorm stats ----------------
__global__ __launch_bounds__(256) void bnstats_k(const float* __restrict__ z,
                                                 float* __restrict__ sums,
                                                 float* __restrict__ sumsq) {
    __shared__ float ls[128], lq[128];
    int f = threadIdx.x & 127;
    int sub = threadIdx.x >> 7;
    float s = 0.f, q = 0.f;
    for (int r = blockIdx.x * 2 + sub; r < NN; r += gridDim.x * 2) {
        float v = z[(size_t)r * 128 + f];
        s += v;
        q += v * v;
    }
    if (sub) { ls[f] = s; lq[f] = q; }
    __syncthreads();
    if (!sub) {
        atomicAdd(&sums[f], s + ls[f]);
        atomicAdd(&sumsq[f], q + lq[f]);
    }
}

__global__ void bnfinal_k(const float* __restrict__ sums, const float* __restrict__ sumsq,
                          const float* __restrict__ gamma, const float* __restrict__ beta,
                          float* __restrict__ bnA, float* __restrict__ bnC) {
    int f = threadIdx.x;
    if (f < 128) {
        float mean = sums[f] * (1.0f / NN);
        float var = sumsq[f] * (1.0f / NN) - mean * mean;
        float a = gamma[f] * rsqrtf(var + BN_EPS);
        bnA[f] = a;
        bnC[f] = beta[f] - mean * a;
    }
}

// ---------------- edge head (dst-grouped over CSR) ----------------
// Wave per node; indices via vector load + readlane; 4 P-gathers in flight;
// ea on scalar pipe; We in VGPRs.
__global__ __launch_bounds__(256) void edgehead_k(const unsigned int* __restrict__ Pb,
                                                  const float* __restrict__ Q,
                                                  const float* __restrict__ ea,
                                                  const int* __restrict__ offsets,
                                                  const int* __restrict__ counts,
                                                  const int2* __restrict__ pairs,
                                                  const float* __restrict__ We,   // [16][128]
                                                  const float* __restrict__ bm1,
                                                  const float* __restrict__ Wm2,
                                                  const float* __restrict__ bm2,
                                                  float* __restrict__ out) {
    int lane = threadIdx.x & 63;
    int n = __builtin_amdgcn_readfirstlane(blockIdx.x * 4 + (threadIdx.x >> 6));
    if (n >= NN) return;
    int beg = offsets[n];
    int cnt = counts[n];
    if (cnt == 0) return;
    int f = lane * 2;
    v2f wreg[16];
#pragma unroll
    for (int k = 0; k < 16; k++) {
        float2 w = *(const float2*)&We[k * 128 + f];
        wreg[k].x = w.x; wreg[k].y = w.y;
    }
    float2 qv = *(const float2*)&Q[(size_t)n * 128 + f];
    float2 bv = *(const float2*)&bm1[f];
    float2 wv = *(const float2*)&Wm2[f];
    float bm2v = bm2[0];
    v2f qb;
    qb.x = qv.x + bv.x;
    qb.y = qv.y + bv.y;

    for (int c = 0; c < cnt; c += 64) {
        int2 pr = pairs[beg + c + lane];   // one coalesced load covers 64 edges
        int m = min(64, cnt - c);
        int t = 0;
        for (; t + 4 <= m; t += 4) {
            int s0 = __builtin_amdgcn_readlane(pr.x, t);
            int s1 = __builtin_amdgcn_readlane(pr.x, t + 1);
            int s2 = __builtin_amdgcn_readlane(pr.x, t + 2);
            int s3 = __builtin_amdgcn_readlane(pr.x, t + 3);
            int e0 = __builtin_amdgcn_readlane(pr.y, t);
            int e1 = __builtin_amdgcn_readlane(pr.y, t + 1);
            int e2 = __builtin_amdgcn_readlane(pr.y, t + 2);
            int e3 = __builtin_amdgcn_readlane(pr.y, t + 3);
            unsigned int u0 = Pb[(size_t)s0 * 64 + lane];
            unsigned int u1 = Pb[(size_t)s1 * 64 + lane];
            unsigned int u2 = Pb[(size_t)s2 * 64 + lane];
            unsigned int u3 = Pb[(size_t)s3 * 64 + lane];
            const float* ea0 = ea + (size_t)e0 * 16;
            const float* ea1 = ea + (size_t)e1 * 16;
            const float* ea2 = ea + (size_t)e2 * 16;
            const float* ea3 = ea + (size_t)e3 * 16;
            v2f a0 = qb + unpackbf2(u0);
            v2f a1 = qb + unpackbf2(u1);
            v2f a2 = qb + unpackbf2(u2);
            v2f a3 = qb + unpackbf2(u3);
#pragma unroll
            for (int k = 0; k < 16; k++) {
                a0 += wreg[k] * ea0[k];
                a1 += wreg[k] * ea1[k];
                a2 += wreg[k] * ea2[k];
                a3 += wreg[k] * ea3[k];
            }
            float v0 = fmaxf(a0.x, 0.f) * wv.x + fmaxf(a0.y, 0.f) * wv.y;
            float v1 = fmaxf(a1.x, 0.f) * wv.x + fmaxf(a1.y, 0.f) * wv.y;
            float v2 = fmaxf(a2.x, 0.f) * wv.x + fmaxf(a2.y, 0.f) * wv.y;
            float v3 = fmaxf(a3.x, 0.f) * wv.x + fmaxf(a3.y, 0.f) * wv.y;
#pragma unroll
            for (int off = 32; off; off >>= 1) {
                v0 += __shfl_xor(v0, off, 64);
                v1 += __shfl_xor(v1, off, 64);
                v2 += __shfl_xor(v2, off, 64);
                v3 += __shfl_xor(v3, off, 64);
            }
            if (lane == 0) {
                out[e0] = v0 + bm2v;
                out[e1] = v1 + bm2v;
                out[e2] = v2 + bm2v;
                out[e3] = v3 + bm2v;
            }
        }
        for (; t < m; t++) {
            int s0 = __builtin_amdgcn_readlane(pr.x, t);
            int e0 = __builtin_amdgcn_readlane(pr.y, t);
            unsigned int u0 = Pb[(size_t)s0 * 64 + lane];
            const float* ea0 = ea + (size_t)e0 * 16;
            v2f a0 = qb + unpackbf2(u0);
#pragma unroll
            for (int k = 0; k < 16; k++) a0 += wreg[k] * ea0[k];
            float v0 = fmaxf(a0.x, 0.f) * wv.x + fmaxf(a0.y, 0.f) * wv.y;
#pragma unroll
            for (int off = 32; off; off >>= 1) v0 += __shfl_xor(v0, off, 64);
            if (lane == 0) out[e0] = v0 + bm2v;
        }
    }
}

// ---------------- launcher ----------------
extern "C" void kernel_launch(void* const* d_in, const int* in_sizes, int n_in,
                              void* d_out, int out_size, void* d_ws, size_t ws_size,
                              hipStream_t stream) {
    const float* x     = (const float*)d_in[0];
    const int*   ei    = (const int*)d_in[1];
    const float* ea    = (const float*)d_in[2];
    const float* W1    = (const float*)d_in[3];
    const float* b1    = (const float*)d_in[4];
    const float* gamma = (const float*)d_in[5];
    const float* beta  = (const float*)d_in[6];
    const float* W2    = (const float*)d_in[7];
    const float* b2    = (const float*)d_in[8];
    const float* Wm1   = (const float*)d_in[9];
    const float* bm1   = (const float*)d_in[10];
    const float* Wm2   = (const float*)d_in[11];
    const float* bm2   = (const float*)d_in[12];
    float* out = (float*)d_out;

    const int* srcI = ei;
    const int* dstI = ei + NE;

    char* w = (char*)d_ws;
    auto alloc = [&](size_t bytes) {
        char* p = w;
        w += (bytes + 255) & ~(size_t)255;
        return p;
    };
    float* dinv    = (float*)alloc(NN * 4);
    int*   counts  = (int*)alloc(NN * 4);
    int*   offsets = (int*)alloc(NN * 4);
    int*   cursor  = (int*)alloc(NN * 4);
    int*   bsum    = (int*)alloc(256 * 4);
    int2*  pairs   = (int2*)alloc((size_t)(NE + 64) * 8);
    float* sums    = (float*)alloc(128 * 4);
    float* sumsq   = (float*)alloc(128 * 4);
    float* bnA     = (float*)alloc(128 * 4);
    float* bnC     = (float*)alloc(128 * 4);
    short* bt1     = (short*)alloc(128 * 128 * 2);
    short* bt2     = (short*)alloc(128 * 128 * 2);
    short* bts     = (short*)alloc(128 * 128 * 2);
    short* btd     = (short*)alloc(128 * 128 * 2);
    unsigned int* hsb = (unsigned int*)alloc((size_t)NN * 64 * 4);
    float* bufZ    = (float*)alloc((size_t)NN * 128 * 4);

    hipMemsetAsync(counts, 0, NN * 4, stream);
    hipMemsetAsync(sums, 0, 128 * 4, stream);
    hipMemsetAsync(sumsq, 0, 128 * 4, stream);

    hist_k<<<(NE + 255) / 256, 256, 0, stream>>>(dstI, counts);
    scan1_k<<<NB_SCAN, 256, 0, stream>>>(counts, bsum);
    scan2_k<<<1, 256, 0, stream>>>(bsum);
    scan3_k<<<NB_SCAN, 256, 0, stream>>>(counts, bsum, offsets, cursor, dinv);
    fill_k<<<(NE + 255) / 256, 256, 0, stream>>>(srcI, dstI, cursor, pairs);
    cvtB_k<<<dim3(64, 4), 256, 0, stream>>>(W1, W2, Wm1, Wm1 + 128 * 128,
                                            bt1, bt2, bts, btd);

    const int GB = (NN + 63) / 64;   // 782
    const int AGG = (NN + 3) / 4;

    // conv1: hs1 = (x@W1)*dinv -> bf16 ; z1 -> bufZ
    gemm_mfma<<<GB, 256, 0, stream>>>(x, bt1, nullptr, hsb, dinv, nullptr, nullptr, NN);
    aggregate_k<<<AGG, 256, 0, stream>>>(hsb, offsets, counts, pairs, dinv, b1, bufZ);

    // BN stats (apply fused into conv2 A-frag load)
    bnstats_k<<<256, 256, 0, stream>>>(bufZ, sums, sumsq);
    bnfinal_k<<<1, 128, 0, stream>>>(sums, sumsq, gamma, beta, bnA, bnC);

    // conv2: hs2 = (relu(bn(z1))@W2)*dinv -> bf16 ; z2 -> bufZ
    gemm_mfma<<<GB, 256, 0, stream>>>(bufZ, bt2, nullptr, hsb, dinv, bnA, bnC, NN);
    aggregate_k<<<AGG, 256, 0, stream>>>(hsb, offsets, counts, pairs, dinv, b2, bufZ);

    // edge head precompute: P = z2@Ws -> bf16 (hsb reused); Q = z2@Wd -> bufZ in-place
    gemm_pq<<<GB, 256, 0, stream>>>(bufZ, bts, btd, hsb, bufZ, NN);

    edgehead_k<<<AGG, 256, 0, stream>>>(hsb, bufZ, ea, offsets, counts, pairs,
                                        Wm1 + 256 * 128, bm1, Wm2, bm2, out);
}

// Round 8
// 511.382 us; speedup vs baseline: 1.2951x; 1.0275x over previous
//
#include <hip/hip_runtime.h>
#include <hip/hip_bf16.h>

#define NN 50000
#define NE 800000
#define H 128
#define DE 16
#define BN_EPS 1e-5f
#define NB_SCAN 196   // ceil(50000/256)

typedef float v2f __attribute__((ext_vector_type(2)));
typedef float v4f __attribute__((ext_vector_type(4)));
typedef short bfrag __attribute__((ext_vector_type(8)));   // 8 bf16 = 4 VGPRs

__device__ __forceinline__ unsigned int packbf2(float a, float b) {
    __hip_bfloat162 h = __float22bfloat162_rn(make_float2(a, b));
    return *(unsigned int*)&h;
}
__device__ __forceinline__ v2f unpackbf2(unsigned int u) {
    v2f r;
    r.x = __uint_as_float(u << 16);
    r.y = __uint_as_float(u & 0xffff0000u);
    return r;
}
__device__ __forceinline__ bfrag cvt8(float4 a0, float4 a1) {
    union { uint4 u; bfrag f; } x;
    x.u.x = packbf2(a0.x, a0.y);
    x.u.y = packbf2(a0.z, a0.w);
    x.u.z = packbf2(a1.x, a1.y);
    x.u.w = packbf2(a1.z, a1.w);
    return x.f;
}
__device__ __forceinline__ float rdlanef(float v, int l) {
    return __uint_as_float(__builtin_amdgcn_readlane(__float_as_uint(v), l));
}

// ---------------- CSR build ----------------
__global__ void hist_k(const int* __restrict__ dst, int* __restrict__ counts) {
    int e = blockIdx.x * 256 + threadIdx.x;
    if (e < NE) atomicAdd(&counts[dst[e]], 1);
}

// hierarchical coalesced scan (3 phases); dinv folded into phase 3
__global__ void scan1_k(const int* __restrict__ counts, int* __restrict__ bsum) {
    __shared__ int sh[256];
    int i = blockIdx.x * 256 + threadIdx.x;
    int v = (i < NN) ? counts[i] : 0;
    sh[threadIdx.x] = v;
    __syncthreads();
    for (int off = 128; off; off >>= 1) {
        if (threadIdx.x < off) sh[threadIdx.x] += sh[threadIdx.x + off];
        __syncthreads();
    }
    if (!threadIdx.x) bsum[blockIdx.x] = sh[0];
}

__global__ void scan2_k(int* __restrict__ bsum) {
    __shared__ int sh[256];
    int t = threadIdx.x;
    int v = (t < NB_SCAN) ? bsum[t] : 0;
    sh[t] = v;
    __syncthreads();
    for (int off = 1; off < 256; off <<= 1) {
        int x = (t >= off) ? sh[t - off] : 0;
        __syncthreads();
        sh[t] += x;
        __syncthreads();
    }
    if (t < NB_SCAN) bsum[t] = sh[t] - v;  // exclusive
}

__global__ void scan3_k(const int* __restrict__ counts, const int* __restrict__ bsum,
                        int* __restrict__ offsets, int* __restrict__ cursor,
                        float* __restrict__ dinv) {
    __shared__ int sh[256];
    int i = blockIdx.x * 256 + threadIdx.x;
    int v = (i < NN) ? counts[i] : 0;
    sh[threadIdx.x] = v;
    __syncthreads();
    for (int off = 1; off < 256; off <<= 1) {
        int x = (threadIdx.x >= off) ? sh[threadIdx.x - off] : 0;
        __syncthreads();
        sh[threadIdx.x] += x;
        __syncthreads();
    }
    if (i < NN) {
        int excl = sh[threadIdx.x] - v + bsum[blockIdx.x];
        offsets[i] = excl;
        cursor[i] = excl;
        dinv[i] = rsqrtf((float)v + 1.0f);
    }
}

// CSR payload: (src, original edge id); pad 64 entries so 64-wide vector loads are safe
__global__ void fill_k(const int* __restrict__ src, const int* __restrict__ dst,
                       int* __restrict__ cursor, int2* __restrict__ pairs) {
    int e = blockIdx.x * 256 + threadIdx.x;
    if (e < NE) {
        int pos = atomicAdd(&cursor[dst[e]], 1);
        pairs[pos] = make_int2(src[e], e);
        if (e < 64) pairs[NE + e] = make_int2(0, 0);
    }
}

// ---------------- B preconvert: Bt[n][k] = bf16(B[k][n]) ----------------
__global__ void cvtB_k(const float* __restrict__ s0, const float* __restrict__ s1,
                       const float* __restrict__ s2, const float* __restrict__ s3,
                       short* __restrict__ d0, short* __restrict__ d1,
                       short* __restrict__ d2, short* __restrict__ d3) {
    const float* s = blockIdx.y == 0 ? s0 : blockIdx.y == 1 ? s1 : blockIdx.y == 2 ? s2 : s3;
    short* d = blockIdx.y == 0 ? d0 : blockIdx.y == 1 ? d1 : blockIdx.y == 2 ? d2 : d3;
    int idx = blockIdx.x * 256 + threadIdx.x;   // 16384
    int n = idx & 127, k = idx >> 7;
    float v = s[k * 128 + n];
    d[n * 128 + k] = (short)(packbf2(v, v) & 0xffff);
}

// ---------------- MFMA GEMM: C[M x 128] = A'[M x 128] @ B[128 x 128] ----------------
__global__ __launch_bounds__(256) void gemm_mfma(const float* __restrict__ A,
                                                 const short* __restrict__ Bt,
                                                 float* __restrict__ C,
                                                 unsigned int* __restrict__ Cb,
                                                 const float* __restrict__ rowScale,
                                                 const float* __restrict__ tA,
                                                 const float* __restrict__ tC,
                                                 int M) {
    int lane = threadIdx.x & 63;
    int w = threadIdx.x >> 6;
    int i = lane & 15;
    int q = lane >> 4;
    int r0 = blockIdx.x * 64 + w * 16;
    int arow = min(r0 + i, M - 1);
    const float* Arow = A + (size_t)arow * 128;

    v4f acc[8];
#pragma unroll
    for (int c = 0; c < 8; c++) acc[c] = (v4f)0.f;

#pragma unroll
    for (int kc = 0; kc < 128; kc += 32) {
        int kb = kc + q * 8;
        float4 a0 = *(const float4*)&Arow[kb];
        float4 a1 = *(const float4*)&Arow[kb + 4];
        if (tA) {
            float4 t0 = *(const float4*)&tA[kb];
            float4 t1 = *(const float4*)&tA[kb + 4];
            float4 c0 = *(const float4*)&tC[kb];
            float4 c1 = *(const float4*)&tC[kb + 4];
            a0.x = fmaxf(a0.x * t0.x + c0.x, 0.f);
            a0.y = fmaxf(a0.y * t0.y + c0.y, 0.f);
            a0.z = fmaxf(a0.z * t0.z + c0.z, 0.f);
            a0.w = fmaxf(a0.w * t0.w + c0.w, 0.f);
            a1.x = fmaxf(a1.x * t1.x + c1.x, 0.f);
            a1.y = fmaxf(a1.y * t1.y + c1.y, 0.f);
            a1.z = fmaxf(a1.z * t1.z + c1.z, 0.f);
            a1.w = fmaxf(a1.w * t1.w + c1.w, 0.f);
        }
        bfrag af = cvt8(a0, a1);
#pragma unroll
        for (int c = 0; c < 8; c++) {
            bfrag bf = *(const bfrag*)&Bt[(size_t)(c * 16 + i) * 128 + kb];
            acc[c] = __builtin_amdgcn_mfma_f32_16x16x32_bf16(af, bf, acc[c], 0, 0, 0);
        }
    }

    int orow0 = r0 + q * 4;
    v4f ds = (v4f)1.f;
    if (rowScale) ds = *(const v4f*)&rowScale[min(orow0, M - 4)];
    if (Cb) {
#pragma unroll
        for (int c = 0; c < 8; c++) {
            int col = c * 16 + i;
#pragma unroll
            for (int r = 0; r < 4; r++) {
                float v = acc[c][r] * ds[r];
                float vp = __shfl_xor(v, 1, 64);
                if (!(i & 1) && orow0 + r < M)
                    Cb[(size_t)(orow0 + r) * 64 + (col >> 1)] = packbf2(v, vp);
            }
        }
    } else {
#pragma unroll
        for (int c = 0; c < 8; c++) {
            int col = c * 16 + i;
#pragma unroll
            for (int r = 0; r < 4; r++) {
                if (orow0 + r < M)
                    C[(size_t)(orow0 + r) * 128 + col] = acc[c][r] * ds[r];
            }
        }
    }
}

// ---------------- merged P/Q MFMA GEMM: P(bf16)=A@Bs, Q(fp32, in-place ok)=A@Bd ----------
__global__ __launch_bounds__(256) void gemm_pq(const float* __restrict__ A,
                                               const short* __restrict__ Bs_,
                                               const short* __restrict__ Bd_,
                                               unsigned int* __restrict__ Pb,
                                               float* __restrict__ Qout,
                                               int M) {
    int lane = threadIdx.x & 63;
    int w = threadIdx.x >> 6;
    int i = lane & 15;
    int q = lane >> 4;
    int r0 = blockIdx.x * 64 + w * 16;
    int arow = min(r0 + i, M - 1);
    const float* Arow = A + (size_t)arow * 128;

    v4f accP[8], accQ[8];
#pragma unroll
    for (int c = 0; c < 8; c++) { accP[c] = (v4f)0.f; accQ[c] = (v4f)0.f; }

#pragma unroll
    for (int kc = 0; kc < 128; kc += 32) {
        int kb = kc + q * 8;
        float4 a0 = *(const float4*)&Arow[kb];
        float4 a1 = *(const float4*)&Arow[kb + 4];
        bfrag af = cvt8(a0, a1);
#pragma unroll
        for (int c = 0; c < 8; c++) {
            bfrag bs = *(const bfrag*)&Bs_[(size_t)(c * 16 + i) * 128 + kb];
            bfrag bd = *(const bfrag*)&Bd_[(size_t)(c * 16 + i) * 128 + kb];
            accP[c] = __builtin_amdgcn_mfma_f32_16x16x32_bf16(af, bs, accP[c], 0, 0, 0);
            accQ[c] = __builtin_amdgcn_mfma_f32_16x16x32_bf16(af, bd, accQ[c], 0, 0, 0);
        }
    }

    int orow0 = r0 + q * 4;
#pragma unroll
    for (int c = 0; c < 8; c++) {
        int col = c * 16 + i;
#pragma unroll
        for (int r = 0; r < 4; r++) {
            float v = accP[c][r];
            float vp = __shfl_xor(v, 1, 64);
            if (orow0 + r < M) {
                if (!(i & 1))
                    Pb[(size_t)(orow0 + r) * 64 + (col >> 1)] = packbf2(v, vp);
                Qout[(size_t)(orow0 + r) * 128 + col] = accQ[c][r];
            }
        }
    }
}

// ---------------- aggregation: z[n] = dinv[n]*(sum_{e->n} hs[src] + hs[n]) + b ----------------
__global__ __launch_bounds__(256, 8) void aggregate_k(const unsigned int* __restrict__ hsb,
                                                      const int* __restrict__ offsets,
                                                      const int* __restrict__ counts,
                                                      const int2* __restrict__ pairs,
                                                      const float* __restrict__ dinv,
                                                      const float* __restrict__ bias,
                                                      float* __restrict__ zout) {
    int lane = threadIdx.x & 63;
    int n = __builtin_amdgcn_readfirstlane(blockIdx.x * 4 + (threadIdx.x >> 6));
    if (n >= NN) return;
    int beg = offsets[n];
    int cnt = counts[n];
    v2f a0 = {0.f, 0.f}, a1 = {0.f, 0.f}, a2 = {0.f, 0.f}, a3 = {0.f, 0.f};
    v2f a4 = {0.f, 0.f}, a5 = {0.f, 0.f}, a6 = {0.f, 0.f}, a7 = {0.f, 0.f};
    for (int c = 0; c < cnt; c += 64) {
        int vsrc = pairs[beg + c + lane].x;   // one coalesced load covers 64 edges
        int m = min(64, cnt - c);
        int t = 0;
        for (; t + 8 <= m; t += 8) {
            int s0 = __builtin_amdgcn_readlane(vsrc, t);
            int s1 = __builtin_amdgcn_readlane(vsrc, t + 1);
            int s2 = __builtin_amdgcn_readlane(vsrc, t + 2);
            int s3 = __builtin_amdgcn_readlane(vsrc, t + 3);
            int s4 = __builtin_amdgcn_readlane(vsrc, t + 4);
            int s5 = __builtin_amdgcn_readlane(vsrc, t + 5);
            int s6 = __builtin_amdgcn_readlane(vsrc, t + 6);
            int s7 = __builtin_amdgcn_readlane(vsrc, t + 7);
            unsigned int u0 = hsb[(size_t)s0 * 64 + lane];
            unsigned int u1 = hsb[(size_t)s1 * 64 + lane];
            unsigned int u2 = hsb[(size_t)s2 * 64 + lane];
            unsigned int u3 = hsb[(size_t)s3 * 64 + lane];
            unsigned int u4 = hsb[(size_t)s4 * 64 + lane];
            unsigned int u5 = hsb[(size_t)s5 * 64 + lane];
            unsigned int u6 = hsb[(size_t)s6 * 64 + lane];
            unsigned int u7 = hsb[(size_t)s7 * 64 + lane];
            a0 += unpackbf2(u0);
            a1 += unpackbf2(u1);
            a2 += unpackbf2(u2);
            a3 += unpackbf2(u3);
            a4 += unpackbf2(u4);
            a5 += unpackbf2(u5);
            a6 += unpackbf2(u6);
            a7 += unpackbf2(u7);
        }
        for (; t < m; t++) {
            int s0 = __builtin_amdgcn_readlane(vsrc, t);
            a0 += unpackbf2(hsb[(size_t)s0 * 64 + lane]);
        }
    }
    v2f self = unpackbf2(hsb[(size_t)n * 64 + lane]);
    float di = dinv[n];
    int f = lane * 2;
    float2 b = *(const float2*)&bias[f];
    v2f sum = ((a0 + a1) + (a2 + a3)) + ((a4 + a5) + (a6 + a7)) + self;
    float2 r;
    r.x = sum.x * di + b.x;
    r.y = sum.y * di + b.y;
    *(float2*)&zout[(size_t)n * 128 + f] = r;
}

// ---------------- BatchNorm stats ----------------
__global__ __launch_bounds__(256) void bnstats_k(const float* __restrict__ z,
                                                 float* __restrict__ sums,
                                                 float* __restrict__ sumsq) {
    __shared__ float ls[128], lq[128];
    int f = threadIdx.x & 127;
    int sub = threadIdx.x >> 7;
    float s = 0.f, q = 0.f;
    for (int r = blockIdx.x * 2 + sub; r < NN; r += gridDim.x * 2) {
        float v = z[(size_t)r * 128 + f];
        s += v;
        q += v * v;
    }
    if (sub) { ls[f] = s; lq[f] = q; }
    __syncthreads();
    if (!sub) {
        atomicAdd(&sums[f], s + ls[f]);
        atomicAdd(&sumsq[f], q + lq[f]);
    }
}

__global__ void bnfinal_k(const float* __restrict__ sums, const float* __restrict__ sumsq,
                          const float* __restrict__ gamma, const float* __restrict__ beta,
                          float* __restrict__ bnA, float* __restrict__ bnC) {
    int f = threadIdx.x;
    if (f < 128) {
        float mean = sums[f] * (1.0f / NN);
        float var = sumsq[f] * (1.0f / NN) - mean * mean;
        float a = gamma[f] * rsqrtf(var + BN_EPS);
        bnA[f] = a;
        bnC[f] = beta[f] - mean * a;
    }
}

// ---------------- edge head (dst-grouped over CSR) ----------------
// Wave per node. Per 8-edge block: ONE vector load fetches all 8 edges' ea rows
// (lane g=lane>>3 -> edge t+g, float2 at comp (lane&7)*2); ea values broadcast by
// v_readlane (VALU, no memory latency); 8 P-gathers in flight. Loads are issued
// unconditionally (pairs padded); out-of-range slots masked at the out[] write.
__global__ __launch_bounds__(256) void edgehead_k(const unsigned int* __restrict__ Pb,
                                                  const float* __restrict__ Q,
                                                  const float* __restrict__ ea,
                                                  const int* __restrict__ offsets,
                                                  const int* __restrict__ counts,
                                                  const int2* __restrict__ pairs,
                                                  const float* __restrict__ We,   // [16][128]
                                                  const float* __restrict__ bm1,
                                                  const float* __restrict__ Wm2,
                                                  const float* __restrict__ bm2,
                                                  float* __restrict__ out) {
    int lane = threadIdx.x & 63;
    int n = __builtin_amdgcn_readfirstlane(blockIdx.x * 4 + (threadIdx.x >> 6));
    if (n >= NN) return;
    int beg = offsets[n];
    int cnt = counts[n];
    if (cnt == 0) return;
    int f = lane * 2;
    v2f wreg[16];
#pragma unroll
    for (int k = 0; k < 16; k++) {
        float2 w = *(const float2*)&We[k * 128 + f];
        wreg[k].x = w.x; wreg[k].y = w.y;
    }
    float2 qv = *(const float2*)&Q[(size_t)n * 128 + f];
    float2 bv = *(const float2*)&bm1[f];
    float2 wv = *(const float2*)&Wm2[f];
    float bm2v = bm2[0];
    v2f qb;
    qb.x = qv.x + bv.x;
    qb.y = qv.y + bv.y;

    for (int c = 0; c < cnt; c += 64) {
        int2 pr = pairs[beg + c + lane];   // one coalesced load covers 64 edges
        int m = min(64, cnt - c);
        for (int t = 0; t < m; t += 8) {
            // ea block: lane group g handles edge t+g; reads past m hit valid
            // (next node's / padding) entries and are discarded.
            int eg = __shfl(pr.y, t + (lane >> 3), 64);
            float2 eav = *(const float2*)&ea[(size_t)eg * 16 + (lane & 7) * 2];
            // 8 P gathers in flight (SGPR base + lane offset)
            int s0 = __builtin_amdgcn_readlane(pr.x, t);
            int s1 = __builtin_amdgcn_readlane(pr.x, t + 1);
            int s2 = __builtin_amdgcn_readlane(pr.x, t + 2);
            int s3 = __builtin_amdgcn_readlane(pr.x, t + 3);
            int s4 = __builtin_amdgcn_readlane(pr.x, t + 4);
            int s5 = __builtin_amdgcn_readlane(pr.x, t + 5);
            int s6 = __builtin_amdgcn_readlane(pr.x, t + 6);
            int s7 = __builtin_amdgcn_readlane(pr.x, t + 7);
            unsigned int u[8];
            u[0] = Pb[(size_t)s0 * 64 + lane];
            u[1] = Pb[(size_t)s1 * 64 + lane];
            u[2] = Pb[(size_t)s2 * 64 + lane];
            u[3] = Pb[(size_t)s3 * 64 + lane];
            u[4] = Pb[(size_t)s4 * 64 + lane];
            u[5] = Pb[(size_t)s5 * 64 + lane];
            u[6] = Pb[(size_t)s6 * 64 + lane];
            u[7] = Pb[(size_t)s7 * 64 + lane];
            float vres[8];
#pragma unroll
            for (int j = 0; j < 8; j++) {
                v2f a = qb + unpackbf2(u[j]);
#pragma unroll
                for (int k = 0; k < 16; k++) {
                    // ea[e_{t+j}][k] lives in lane j*8 + (k>>1), comp k&1
                    float ek = rdlanef((k & 1) ? eav.y : eav.x, j * 8 + (k >> 1));
                    a += wreg[k] * ek;
                }
                vres[j] = fmaxf(a.x, 0.f) * wv.x + fmaxf(a.y, 0.f) * wv.y;
            }
#pragma unroll
            for (int off = 32; off; off >>= 1) {
#pragma unroll
                for (int j = 0; j < 8; j++) vres[j] += __shfl_xor(vres[j], off, 64);
            }
            if (lane == 0) {
#pragma unroll
                for (int j = 0; j < 8; j++) {
                    if (t + j < m) {
                        int e = __builtin_amdgcn_readlane(pr.y, t + j);
                        out[e] = vres[j] + bm2v;
                    }
                }
            }
        }
    }
}

// ---------------- launcher ----------------
extern "C" void kernel_launch(void* const* d_in, const int* in_sizes, int n_in,
                              void* d_out, int out_size, void* d_ws, size_t ws_size,
                              hipStream_t stream) {
    const float* x     = (const float*)d_in[0];
    const int*   ei    = (const int*)d_in[1];
    const float* ea    = (const float*)d_in[2];
    const float* W1    = (const float*)d_in[3];
    const float* b1    = (const float*)d_in[4];
    const float* gamma = (const float*)d_in[5];
    const float* beta  = (const float*)d_in[6];
    const float* W2    = (const float*)d_in[7];
    const float* b2    = (const float*)d_in[8];
    const float* Wm1   = (const float*)d_in[9];
    const float* bm1   = (const float*)d_in[10];
    const float* Wm2   = (const float*)d_in[11];
    const float* bm2   = (const float*)d_in[12];
    float* out = (float*)d_out;

    const int* srcI = ei;
    const int* dstI = ei + NE;

    char* w = (char*)d_ws;
    auto alloc = [&](size_t bytes) {
        char* p = w;
        w += (bytes + 255) & ~(size_t)255;
        return p;
    };
    float* dinv    = (float*)alloc(NN * 4);
    int*   counts  = (int*)alloc(NN * 4);
    int*   offsets = (int*)alloc(NN * 4);
    int*   cursor  = (int*)alloc(NN * 4);
    int*   bsum    = (int*)alloc(256 * 4);
    int2*  pairs   = (int2*)alloc((size_t)(NE + 64) * 8);
    float* sums    = (float*)alloc(128 * 4);
    float* sumsq   = (float*)alloc(128 * 4);
    float* bnA     = (float*)alloc(128 * 4);
    float* bnC     = (float*)alloc(128 * 4);
    short* bt1     = (short*)alloc(128 * 128 * 2);
    short* bt2     = (short*)alloc(128 * 128 * 2);
    short* bts     = (short*)alloc(128 * 128 * 2);
    short* btd     = (short*)alloc(128 * 128 * 2);
    unsigned int* hsb = (unsigned int*)alloc((size_t)NN * 64 * 4);
    float* bufZ    = (float*)alloc((size_t)NN * 128 * 4);

    hipMemsetAsync(counts, 0, NN * 4, stream);
    hipMemsetAsync(sums, 0, 128 * 4, stream);
    hipMemsetAsync(sumsq, 0, 128 * 4, stream);

    hist_k<<<(NE + 255) / 256, 256, 0, stream>>>(dstI, counts);
    scan1_k<<<NB_SCAN, 256, 0, stream>>>(counts, bsum);
    scan2_k<<<1, 256, 0, stream>>>(bsum);
    scan3_k<<<NB_SCAN, 256, 0, stream>>>(counts, bsum, offsets, cursor, dinv);
    fill_k<<<(NE + 255) / 256, 256, 0, stream>>>(srcI, dstI, cursor, pairs);
    cvtB_k<<<dim3(64, 4), 256, 0, stream>>>(W1, W2, Wm1, Wm1 + 128 * 128,
                                            bt1, bt2, bts, btd);

    const int GB = (NN + 63) / 64;   // 782
    const int AGG = (NN + 3) / 4;

    // conv1: hs1 = (x@W1)*dinv -> bf16 ; z1 -> bufZ
    gemm_mfma<<<GB, 256, 0, stream>>>(x, bt1, nullptr, hsb, dinv, nullptr, nullptr, NN);
    aggregate_k<<<AGG, 256, 0, stream>>>(hsb, offsets, counts, pairs, dinv, b1, bufZ);

    // BN stats (apply fused into conv2 A-frag load)
    bnstats_k<<<256, 256, 0, stream>>>(bufZ, sums, sumsq);
    bnfinal_k<<<1, 128, 0, stream>>>(sums, sumsq, gamma, beta, bnA, bnC);

    // conv2: hs2 = (relu(bn(z1))@W2)*dinv -> bf16 ; z2 -> bufZ
    gemm_mfma<<<GB, 256, 0, stream>>>(bufZ, bt2, nullptr, hsb, dinv, bnA, bnC, NN);
    aggregate_k<<<AGG, 256, 0, stream>>>(hsb, offsets, counts, pairs, dinv, b2, bufZ);

    // edge head precompute: P = z2@Ws -> bf16 (hsb reused); Q = z2@Wd -> bufZ in-place
    gemm_pq<<<GB, 256, 0, stream>>>(bufZ, bts, btd, hsb, bufZ, NN);

    edgehead_k<<<AGG, 256, 0, stream>>>(hsb, bufZ, ea, offsets, counts, pairs,
                                        Wm1 + 256 * 128, bm1, Wm2, bm2, out);
}

// Round 9
// 471.129 us; speedup vs baseline: 1.4058x; 1.0854x over previous
//
#include <hip/hip_runtime.h>
#include <hip/hip_bf16.h>

#define NN 50000
#define NE 800000
#define H 128
#define DE 16
#define BN_EPS 1e-5f
#define NB_SCAN 196   // ceil(50000/256)

typedef float v2f __attribute__((ext_vector_type(2)));
typedef float v4f __attribute__((ext_vector_type(4)));
typedef short bfrag __attribute__((ext_vector_type(8)));   // 8 bf16 = 4 VGPRs

__device__ __forceinline__ unsigned int packbf2(float a, float b) {
    __hip_bfloat162 h = __float22bfloat162_rn(make_float2(a, b));
    return *(unsigned int*)&h;
}
__device__ __forceinline__ v2f unpackbf2(unsigned int u) {
    v2f r;
    r.x = __uint_as_float(u << 16);
    r.y = __uint_as_float(u & 0xffff0000u);
    return r;
}
__device__ __forceinline__ bfrag cvt8(float4 a0, float4 a1) {
    union { uint4 u; bfrag f; } x;
    x.u.x = packbf2(a0.x, a0.y);
    x.u.y = packbf2(a0.z, a0.w);
    x.u.z = packbf2(a1.x, a1.y);
    x.u.w = packbf2(a1.z, a1.w);
    return x.f;
}
#define COMP(u4, j) ((j) == 0 ? (u4).x : (j) == 1 ? (u4).y : (j) == 2 ? (u4).z : (u4).w)

// ---------------- CSR build ----------------
__global__ void hist_k(const int* __restrict__ dst, int* __restrict__ counts) {
    int e = blockIdx.x * 256 + threadIdx.x;
    if (e < NE) atomicAdd(&counts[dst[e]], 1);
}

__global__ void scan1_k(const int* __restrict__ counts, int* __restrict__ bsum) {
    __shared__ int sh[256];
    int i = blockIdx.x * 256 + threadIdx.x;
    int v = (i < NN) ? counts[i] : 0;
    sh[threadIdx.x] = v;
    __syncthreads();
    for (int off = 128; off; off >>= 1) {
        if (threadIdx.x < off) sh[threadIdx.x] += sh[threadIdx.x + off];
        __syncthreads();
    }
    if (!threadIdx.x) bsum[blockIdx.x] = sh[0];
}

__global__ void scan2_k(int* __restrict__ bsum) {
    __shared__ int sh[256];
    int t = threadIdx.x;
    int v = (t < NB_SCAN) ? bsum[t] : 0;
    sh[t] = v;
    __syncthreads();
    for (int off = 1; off < 256; off <<= 1) {
        int x = (t >= off) ? sh[t - off] : 0;
        __syncthreads();
        sh[t] += x;
        __syncthreads();
    }
    if (t < NB_SCAN) bsum[t] = sh[t] - v;  // exclusive
}

__global__ void scan3_k(const int* __restrict__ counts, const int* __restrict__ bsum,
                        int* __restrict__ offsets, int* __restrict__ cursor,
                        float* __restrict__ dinv) {
    __shared__ int sh[256];
    int i = blockIdx.x * 256 + threadIdx.x;
    int v = (i < NN) ? counts[i] : 0;
    sh[threadIdx.x] = v;
    __syncthreads();
    for (int off = 1; off < 256; off <<= 1) {
        int x = (threadIdx.x >= off) ? sh[threadIdx.x - off] : 0;
        __syncthreads();
        sh[threadIdx.x] += x;
        __syncthreads();
    }
    if (i < NN) {
        int excl = sh[threadIdx.x] - v + bsum[blockIdx.x];
        offsets[i] = excl;
        cursor[i] = excl;
        dinv[i] = rsqrtf((float)v + 1.0f);
    }
}

// CSR payload: pairs=(src, eid) + separate dst array; pad 64 pairs for aggregate over-read
__global__ void fill_k(const int* __restrict__ src, const int* __restrict__ dst,
                       int* __restrict__ cursor, int2* __restrict__ pairs,
                       int* __restrict__ dste) {
    int e = blockIdx.x * 256 + threadIdx.x;
    if (e < NE) {
        int d = dst[e];
        int pos = atomicAdd(&cursor[d], 1);
        pairs[pos] = make_int2(src[e], e);
        dste[pos] = d;
        if (e < 64) pairs[NE + e] = make_int2(0, 0);
    }
}

// ---------------- B preconvert: Bt[n][k] = bf16(B[k][n]) ----------------
__global__ void cvtB_k(const float* __restrict__ s0, const float* __restrict__ s1,
                       const float* __restrict__ s2, const float* __restrict__ s3,
                       short* __restrict__ d0, short* __restrict__ d1,
                       short* __restrict__ d2, short* __restrict__ d3) {
    const float* s = blockIdx.y == 0 ? s0 : blockIdx.y == 1 ? s1 : blockIdx.y == 2 ? s2 : s3;
    short* d = blockIdx.y == 0 ? d0 : blockIdx.y == 1 ? d1 : blockIdx.y == 2 ? d2 : d3;
    int idx = blockIdx.x * 256 + threadIdx.x;   // 16384
    int n = idx & 127, k = idx >> 7;
    float v = s[k * 128 + n];
    d[n * 128 + k] = (short)(packbf2(v, v) & 0xffff);
}

// ---------------- We B-frag precompute (K padded 16->32, feat perm i*8+c) ----------------
// WePk[((c*64+lane)*4 + ju] = bf16 pair (k = q*8+2*ju, q*8+2*ju+1), value We[k][i*8+c] (0 if k>=16)
__global__ void cvtWe_k(const float* __restrict__ We, unsigned int* __restrict__ WePk) {
    int idx = blockIdx.x * 256 + threadIdx.x;   // 2048
    if (idx < 2048) {
        int c = idx >> 8;
        int lane = (idx >> 2) & 63;
        int j2 = (idx & 3) * 2;
        int q = lane >> 4, i = lane & 15;
        int k0 = q * 8 + j2, k1 = k0 + 1;
        int feat = i * 8 + c;
        float v0 = (k0 < 16) ? We[k0 * 128 + feat] : 0.f;
        float v1 = (k1 < 16) ? We[k1 * 128 + feat] : 0.f;
        WePk[idx] = packbf2(v0, v1);
    }
}

// ---------------- MFMA GEMM: C[M x 128] = A'[M x 128] @ B[128 x 128] ----------------
__global__ __launch_bounds__(256) void gemm_mfma(const float* __restrict__ A,
                                                 const short* __restrict__ Bt,
                                                 float* __restrict__ C,
                                                 unsigned int* __restrict__ Cb,
                                                 const float* __restrict__ rowScale,
                                                 const float* __restrict__ tA,
                                                 const float* __restrict__ tC,
                                                 int M) {
    int lane = threadIdx.x & 63;
    int w = threadIdx.x >> 6;
    int i = lane & 15;
    int q = lane >> 4;
    int r0 = blockIdx.x * 64 + w * 16;
    int arow = min(r0 + i, M - 1);
    const float* Arow = A + (size_t)arow * 128;

    v4f acc[8];
#pragma unroll
    for (int c = 0; c < 8; c++) acc[c] = (v4f)0.f;

#pragma unroll
    for (int kc = 0; kc < 128; kc += 32) {
        int kb = kc + q * 8;
        float4 a0 = *(const float4*)&Arow[kb];
        float4 a1 = *(const float4*)&Arow[kb + 4];
        if (tA) {
            float4 t0 = *(const float4*)&tA[kb];
            float4 t1 = *(const float4*)&tA[kb + 4];
            float4 c0 = *(const float4*)&tC[kb];
            float4 c1 = *(const float4*)&tC[kb + 4];
            a0.x = fmaxf(a0.x * t0.x + c0.x, 0.f);
            a0.y = fmaxf(a0.y * t0.y + c0.y, 0.f);
            a0.z = fmaxf(a0.z * t0.z + c0.z, 0.f);
            a0.w = fmaxf(a0.w * t0.w + c0.w, 0.f);
            a1.x = fmaxf(a1.x * t1.x + c1.x, 0.f);
            a1.y = fmaxf(a1.y * t1.y + c1.y, 0.f);
            a1.z = fmaxf(a1.z * t1.z + c1.z, 0.f);
            a1.w = fmaxf(a1.w * t1.w + c1.w, 0.f);
        }
        bfrag af = cvt8(a0, a1);
#pragma unroll
        for (int c = 0; c < 8; c++) {
            bfrag bf = *(const bfrag*)&Bt[(size_t)(c * 16 + i) * 128 + kb];
            acc[c] = __builtin_amdgcn_mfma_f32_16x16x32_bf16(af, bf, acc[c], 0, 0, 0);
        }
    }

    int orow0 = r0 + q * 4;
    v4f ds = (v4f)1.f;
    if (rowScale) ds = *(const v4f*)&rowScale[min(orow0, M - 4)];
    if (Cb) {
#pragma unroll
        for (int c = 0; c < 8; c++) {
            int col = c * 16 + i;
#pragma unroll
            for (int r = 0; r < 4; r++) {
                float v = acc[c][r] * ds[r];
                float vp = __shfl_xor(v, 1, 64);
                if (!(i & 1) && orow0 + r < M)
                    Cb[(size_t)(orow0 + r) * 64 + (col >> 1)] = packbf2(v, vp);
            }
        }
    } else {
#pragma unroll
        for (int c = 0; c < 8; c++) {
            int col = c * 16 + i;
#pragma unroll
            for (int r = 0; r < 4; r++) {
                if (orow0 + r < M)
                    C[(size_t)(orow0 + r) * 128 + col] = acc[c][r] * ds[r];
            }
        }
    }
}

// ---------------- merged P/Q MFMA GEMM (A bf16-packed): P=A@Bs (bf16), Q=A@Bd+bm1 (bf16) ----
__global__ __launch_bounds__(256) void gemm_pq(const unsigned int* __restrict__ zbA,
                                               const short* __restrict__ Bs_,
                                               const short* __restrict__ Bd_,
                                               const float* __restrict__ bm1,
                                               unsigned int* __restrict__ Pb,
                                               unsigned int* __restrict__ Qb,
                                               int M) {
    int lane = threadIdx.x & 63;
    int w = threadIdx.x >> 6;
    int i = lane & 15;
    int q = lane >> 4;
    int r0 = blockIdx.x * 64 + w * 16;
    int arow = min(r0 + i, M - 1);

    v4f accP[8], accQ[8];
#pragma unroll
    for (int c = 0; c < 8; c++) { accP[c] = (v4f)0.f; accQ[c] = (v4f)0.f; }

#pragma unroll
    for (int kc = 0; kc < 128; kc += 32) {
        int kb = kc + q * 8;
        bfrag af = *(const bfrag*)&zbA[(size_t)arow * 64 + (kb >> 1)];
#pragma unroll
        for (int c = 0; c < 8; c++) {
            bfrag bs = *(const bfrag*)&Bs_[(size_t)(c * 16 + i) * 128 + kb];
            bfrag bd = *(const bfrag*)&Bd_[(size_t)(c * 16 + i) * 128 + kb];
            accP[c] = __builtin_amdgcn_mfma_f32_16x16x32_bf16(af, bs, accP[c], 0, 0, 0);
            accQ[c] = __builtin_amdgcn_mfma_f32_16x16x32_bf16(af, bd, accQ[c], 0, 0, 0);
        }
    }

    int orow0 = r0 + q * 4;
    float bm1c[8];
#pragma unroll
    for (int c = 0; c < 8; c++) bm1c[c] = bm1[c * 16 + i];
#pragma unroll
    for (int c = 0; c < 8; c++) {
        int col = c * 16 + i;
#pragma unroll
        for (int r = 0; r < 4; r++) {
            float vP = accP[c][r];
            float vPp = __shfl_xor(vP, 1, 64);
            float vQ = accQ[c][r] + bm1c[c];
            float vQp = __shfl_xor(vQ, 1, 64);
            if (!(i & 1) && orow0 + r < M) {
                Pb[(size_t)(orow0 + r) * 64 + (col >> 1)] = packbf2(vP, vPp);
                Qb[(size_t)(orow0 + r) * 64 + (col >> 1)] = packbf2(vQ, vQp);
            }
        }
    }
}

// ---------------- aggregation: z[n] = dinv[n]*(sum_{e->n} hs[src] + hs[n]) + b ----------------
// fp32 out (zout) or bf16-packed out (zbout) — exactly one non-null.
__global__ __launch_bounds__(256, 8) void aggregate_k(const unsigned int* __restrict__ hsb,
                                                      const int* __restrict__ offsets,
                                                      const int* __restrict__ counts,
                                                      const int2* __restrict__ pairs,
                                                      const float* __restrict__ dinv,
                                                      const float* __restrict__ bias,
                                                      float* __restrict__ zout,
                                                      unsigned int* __restrict__ zbout) {
    int lane = threadIdx.x & 63;
    int n = __builtin_amdgcn_readfirstlane(blockIdx.x * 4 + (threadIdx.x >> 6));
    if (n >= NN) return;
    int beg = offsets[n];
    int cnt = counts[n];
    v2f a0 = {0.f, 0.f}, a1 = {0.f, 0.f}, a2 = {0.f, 0.f}, a3 = {0.f, 0.f};
    v2f a4 = {0.f, 0.f}, a5 = {0.f, 0.f}, a6 = {0.f, 0.f}, a7 = {0.f, 0.f};
    for (int c = 0; c < cnt; c += 64) {
        int vsrc = pairs[beg + c + lane].x;
        int m = min(64, cnt - c);
        int t = 0;
        for (; t + 8 <= m; t += 8) {
            int s0 = __builtin_amdgcn_readlane(vsrc, t);
            int s1 = __builtin_amdgcn_readlane(vsrc, t + 1);
            int s2 = __builtin_amdgcn_readlane(vsrc, t + 2);
            int s3 = __builtin_amdgcn_readlane(vsrc, t + 3);
            int s4 = __builtin_amdgcn_readlane(vsrc, t + 4);
            int s5 = __builtin_amdgcn_readlane(vsrc, t + 5);
            int s6 = __builtin_amdgcn_readlane(vsrc, t + 6);
            int s7 = __builtin_amdgcn_readlane(vsrc, t + 7);
            unsigned int u0 = hsb[(size_t)s0 * 64 + lane];
            unsigned int u1 = hsb[(size_t)s1 * 64 + lane];
            unsigned int u2 = hsb[(size_t)s2 * 64 + lane];
            unsigned int u3 = hsb[(size_t)s3 * 64 + lane];
            unsigned int u4 = hsb[(size_t)s4 * 64 + lane];
            unsigned int u5 = hsb[(size_t)s5 * 64 + lane];
            unsigned int u6 = hsb[(size_t)s6 * 64 + lane];
            unsigned int u7 = hsb[(size_t)s7 * 64 + lane];
            a0 += unpackbf2(u0);
            a1 += unpackbf2(u1);
            a2 += unpackbf2(u2);
            a3 += unpackbf2(u3);
            a4 += unpackbf2(u4);
            a5 += unpackbf2(u5);
            a6 += unpackbf2(u6);
            a7 += unpackbf2(u7);
        }
        for (; t < m; t++) {
            int s0 = __builtin_amdgcn_readlane(vsrc, t);
            a0 += unpackbf2(hsb[(size_t)s0 * 64 + lane]);
        }
    }
    v2f self = unpackbf2(hsb[(size_t)n * 64 + lane]);
    float di = dinv[n];
    int f = lane * 2;
    float2 b = *(const float2*)&bias[f];
    v2f sum = ((a0 + a1) + (a2 + a3)) + ((a4 + a5) + (a6 + a7)) + self;
    float rx = sum.x * di + b.x;
    float ry = sum.y * di + b.y;
    if (zbout) {
        zbout[(size_t)n * 64 + lane] = packbf2(rx, ry);
    } else {
        *(float2*)&zout[(size_t)n * 128 + f] = make_float2(rx, ry);
    }
}

// ---------------- BatchNorm stats ----------------
__global__ __launch_bounds__(256) void bnstats_k(const float* __restrict__ z,
                                                 float* __restrict__ sums,
                                                 float* __restrict__ sumsq) {
    __shared__ float ls[128], lq[128];
    int f = threadIdx.x & 127;
    int sub = threadIdx.x >> 7;
    float s = 0.f, q = 0.f;
    for (int r = blockIdx.x * 2 + sub; r < NN; r += gridDim.x * 2) {
        float v = z[(size_t)r * 128 + f];
        s += v;
        q += v * v;
    }
    if (sub) { ls[f] = s; lq[f] = q; }
    __syncthreads();
    if (!sub) {
        atomicAdd(&sums[f], s + ls[f]);
        atomicAdd(&sumsq[f], q + lq[f]);
    }
}

__global__ void bnfinal_k(const float* __restrict__ sums, const float* __restrict__ sumsq,
                          const float* __restrict__ gamma, const float* __restrict__ beta,
                          float* __restrict__ bnA, float* __restrict__ bnC) {
    int f = threadIdx.x;
    if (f < 128) {
        float mean = sums[f] * (1.0f / NN);
        float var = sumsq[f] * (1.0f / NN) - mean * mean;
        float a = gamma[f] * rsqrtf(var + BN_EPS);
        bnA[f] = a;
        bnC[f] = beta[f] - mean * a;
    }
}

// ---------------- edge head: MFMA over flat CSR ----------------
// Wave = 64 CSR positions = 4 tiles of 16 edges. Per tile:
//   T = ea_tile(16x16, K-pad 32) @ We_perm  via 8 MFMA (C: row=q*4+r=edge, col-lane i, feat i*8+c)
//   P[src], Q[dst] (bf16, bm1 folded into Q) gathered per edge as uint4/lane in the SAME layout.
//   out[e] = sum_f Wm2[f]*relu(P+Q+T) + bm2  (quad-local 4-step reduction)
__global__ __launch_bounds__(256) void edgehead_k(const unsigned int* __restrict__ Pb,
                                                  const unsigned int* __restrict__ Qb,
                                                  const float* __restrict__ ea,
                                                  const int2* __restrict__ pairs,
                                                  const int* __restrict__ dste,
                                                  const unsigned int* __restrict__ WePk,
                                                  const float* __restrict__ Wm2,
                                                  const float* __restrict__ bm2,
                                                  float* __restrict__ out) {
    int lane = threadIdx.x & 63;
    int wid = threadIdx.x >> 6;
    int base = (blockIdx.x * 4 + wid) * 64;
    int i = lane & 15;
    int q = lane >> 4;

    bfrag wef[8];
#pragma unroll
    for (int c = 0; c < 8; c++)
        wef[c] = *(const bfrag*)&WePk[(c * 64 + lane) * 4];
    float4 wv0 = *(const float4*)&Wm2[i * 8];
    float4 wv1 = *(const float4*)&Wm2[i * 8 + 4];
    float bm2v = bm2[0];

    int2 pr = pairs[base + lane];
    int dv = dste[base + lane];

#pragma unroll
    for (int t = 0; t < 4; t++) {
        int tb = t * 16;
        // A-frag: edge tb+i, k = q*8+j (zero for k>=16)
        int eidA = __shfl(pr.y, tb + i, 64);
        bfrag af;
#pragma unroll
        for (int z = 0; z < 8; z++) af[z] = 0;
        if (q < 2) {
            float4 e0 = *(const float4*)&ea[(size_t)eidA * 16 + q * 8];
            float4 e1 = *(const float4*)&ea[(size_t)eidA * 16 + q * 8 + 4];
            af = cvt8(e0, e1);
        }
        // P/Q gathers in C layout: edge (q,r), lane i holds feats i*8..i*8+7
        uint4 Pu[4], Qu[4];
        int eidw[4];
#pragma unroll
        for (int r = 0; r < 4; r++) {
            int sr = __shfl(pr.x, tb + q * 4 + r, 64);
            int dr = __shfl(dv, tb + q * 4 + r, 64);
            eidw[r] = __shfl(pr.y, tb + q * 4 + r, 64);
            Pu[r] = *(const uint4*)&Pb[(size_t)sr * 64 + i * 4];
            Qu[r] = *(const uint4*)&Qb[(size_t)dr * 64 + i * 4];
        }
        v4f acc[8];
#pragma unroll
        for (int c = 0; c < 8; c++) acc[c] = (v4f)0.f;
#pragma unroll
        for (int c = 0; c < 8; c++)
            acc[c] = __builtin_amdgcn_mfma_f32_16x16x32_bf16(af, wef[c], acc[c], 0, 0, 0);
        // epilogue
        float wvp[8] = {wv0.x, wv0.y, wv0.z, wv0.w, wv1.x, wv1.y, wv1.z, wv1.w};
#pragma unroll
        for (int r = 0; r < 4; r++) {
            float s = 0.f;
#pragma unroll
            for (int j = 0; j < 4; j++) {
                v2f pv = unpackbf2(COMP(Pu[r], j));
                v2f qv = unpackbf2(COMP(Qu[r], j));
                float t0 = acc[2 * j][r] + pv.x + qv.x;
                float t1 = acc[2 * j + 1][r] + pv.y + qv.y;
                t0 = fmaxf(t0, 0.f);
                t1 = fmaxf(t1, 0.f);
                s = fmaf(t0, wvp[2 * j], s);
                s = fmaf(t1, wvp[2 * j + 1], s);
            }
#pragma unroll
            for (int off = 1; off <= 8; off <<= 1) s += __shfl_xor(s, off, 64);
            if (i == 0) out[eidw[r]] = s + bm2v;
        }
    }
}

// ---------------- launcher ----------------
extern "C" void kernel_launch(void* const* d_in, const int* in_sizes, int n_in,
                              void* d_out, int out_size, void* d_ws, size_t ws_size,
                              hipStream_t stream) {
    const float* x     = (const float*)d_in[0];
    const int*   ei    = (const int*)d_in[1];
    const float* ea    = (const float*)d_in[2];
    const float* W1    = (const float*)d_in[3];
    const float* b1    = (const float*)d_in[4];
    const float* gamma = (const float*)d_in[5];
    const float* beta  = (const float*)d_in[6];
    const float* W2    = (const float*)d_in[7];
    const float* b2    = (const float*)d_in[8];
    const float* Wm1   = (const float*)d_in[9];
    const float* bm1   = (const float*)d_in[10];
    const float* Wm2   = (const float*)d_in[11];
    const float* bm2   = (const float*)d_in[12];
    float* out = (float*)d_out;

    const int* srcI = ei;
    const int* dstI = ei + NE;

    char* w = (char*)d_ws;
    auto alloc = [&](size_t bytes) {
        char* p = w;
        w += (bytes + 255) & ~(size_t)255;
        return p;
    };
    float* dinv    = (float*)alloc(NN * 4);
    int*   counts  = (int*)alloc(NN * 4);
    int*   offsets = (int*)alloc(NN * 4);
    int*   cursor  = (int*)alloc(NN * 4);
    int*   bsum    = (int*)alloc(256 * 4);
    int2*  pairs   = (int2*)alloc((size_t)(NE + 64) * 8);
    int*   dste    = (int*)alloc((size_t)NE * 4);
    float* sums    = (float*)alloc(128 * 4);
    float* sumsq   = (float*)alloc(128 * 4);
    float* bnA     = (float*)alloc(128 * 4);
    float* bnC     = (float*)alloc(128 * 4);
    short* bt1     = (short*)alloc(128 * 128 * 2);
    short* bt2     = (short*)alloc(128 * 128 * 2);
    short* bts     = (short*)alloc(128 * 128 * 2);
    short* btd     = (short*)alloc(128 * 128 * 2);
    unsigned int* WePk = (unsigned int*)alloc(2048 * 4);
    unsigned int* hsb  = (unsigned int*)alloc((size_t)NN * 64 * 4);   // hs / P table
    float* bufZ    = (float*)alloc((size_t)NN * 128 * 4);             // z1 fp32; later zb2+Qb
    unsigned int* zb2 = (unsigned int*)bufZ;                          // alias: first half
    unsigned int* Qb  = (unsigned int*)bufZ + (size_t)NN * 64;        // alias: second half

    hipMemsetAsync(counts, 0, NN * 4, stream);
    hipMemsetAsync(sums, 0, 128 * 4, stream);
    hipMemsetAsync(sumsq, 0, 128 * 4, stream);

    hist_k<<<(NE + 255) / 256, 256, 0, stream>>>(dstI, counts);
    scan1_k<<<NB_SCAN, 256, 0, stream>>>(counts, bsum);
    scan2_k<<<1, 256, 0, stream>>>(bsum);
    scan3_k<<<NB_SCAN, 256, 0, stream>>>(counts, bsum, offsets, cursor, dinv);
    fill_k<<<(NE + 255) / 256, 256, 0, stream>>>(srcI, dstI, cursor, pairs, dste);
    cvtB_k<<<dim3(64, 4), 256, 0, stream>>>(W1, W2, Wm1, Wm1 + 128 * 128,
                                            bt1, bt2, bts, btd);
    cvtWe_k<<<8, 256, 0, stream>>>(Wm1 + 256 * 128, WePk);

    const int GB = (NN + 63) / 64;   // 782
    const int AGG = (NN + 3) / 4;

    // conv1: hs1 = (x@W1)*dinv -> bf16 ; z1 -> bufZ (fp32)
    gemm_mfma<<<GB, 256, 0, stream>>>(x, bt1, nullptr, hsb, dinv, nullptr, nullptr, NN);
    aggregate_k<<<AGG, 256, 0, stream>>>(hsb, offsets, counts, pairs, dinv, b1, bufZ, nullptr);

    // BN stats (apply fused into conv2 A-frag load)
    bnstats_k<<<256, 256, 0, stream>>>(bufZ, sums, sumsq);
    bnfinal_k<<<1, 128, 0, stream>>>(sums, sumsq, gamma, beta, bnA, bnC);

    // conv2: hs2 = (relu(bn(z1))@W2)*dinv -> bf16 ; z2 -> zb2 (bf16, aliases bufZ after it's dead)
    gemm_mfma<<<GB, 256, 0, stream>>>(bufZ, bt2, nullptr, hsb, dinv, bnA, bnC, NN);
    aggregate_k<<<AGG, 256, 0, stream>>>(hsb, offsets, counts, pairs, dinv, b2, nullptr, zb2);

    // edge head precompute: P = z2@Ws -> bf16 (hsb reused); Q = z2@Wd + bm1 -> bf16
    gemm_pq<<<GB, 256, 0, stream>>>(zb2, bts, btd, bm1, hsb, Qb, NN);

    // flat MFMA edge head: 800000/64 waves = 3125 blocks
    edgehead_k<<<NE / 256, 256, 0, stream>>>(hsb, Qb, ea, pairs, dste, WePk,
                                             Wm2, bm2, out);
}